// Round 13
// baseline (1404.328 us; speedup 1.0000x reference)
//
#include <hip/hip_runtime.h>
#include <hip/hip_bf16.h>
#include <stdint.h>

#define NN 50000
#define RR 5
#define AA 8
#define FF 128
#define TT 2
#define OO 128
#define KDIM 1024   // 8 planes * F
#define KB 512      // K per half (E or O)
#define RA 40       // R*A

typedef __attribute__((ext_vector_type(8))) short short8;
typedef __attribute__((ext_vector_type(4))) float f32x4;
typedef __attribute__((ext_vector_type(2))) float f32x2;
typedef __attribute__((ext_vector_type(4))) int i32x4;
typedef __attribute__((ext_vector_type(2))) unsigned u32x2;

#if __has_builtin(__builtin_elementwise_fma)
__device__ inline f32x2 pk_fma(f32x2 a, f32x2 b, f32x2 c) {
  return __builtin_elementwise_fma(a, b, c);
}
#else
__device__ inline f32x2 pk_fma(f32x2 a, f32x2 b, f32x2 c) {
  f32x2 d;
  asm("v_pk_fma_f32 %0, %1, %2, %3" : "=v"(d) : "v"(a), "v"(b), "v"(c));
  return d;
}
#endif

__device__ inline void gload_lds16(const void* g, void* l) {
  __builtin_amdgcn_global_load_lds(
      (const __attribute__((address_space(1))) unsigned int*)g,
      (__attribute__((address_space(3))) unsigned int*)l, 16, 0, 0);
}

// ---------- prep: mesh->bf16 sliced, G (radix-2 mix), Bh (E/O weights), packed bary --
__global__ void prep_kernel(const float* __restrict__ mesh,
                            const float* __restrict__ coeffs,
                            const float* __restrict__ W,
                            const float* __restrict__ bary_w,
                            const int* __restrict__ bary_idx,
                            __hip_bfloat16* __restrict__ meshq,  // [4][N][32]
                            float* __restrict__ G,               // [8][40]
                            __hip_bfloat16* __restrict__ Bh,     // [2048][512]
                            unsigned* __restrict__ packb,
                            int do_pack) {
  int tid = blockIdx.x * blockDim.x + threadIdx.x;
  int stride = gridDim.x * blockDim.x;
  for (int i = tid; i < NN * FF; i += stride) {
    int n = i >> 7, f = i & 127;
    int p = f >> 5, fo = f & 31;
    meshq[((long)p * NN + n) * 32 + fo] = __float2bfloat16(mesh[i]);
  }
  // G[p][k]: p<4 -> C2[p]+C2[p+4];  p>=4 -> C2[p-4]-C2[p]   (C2 = sum_r coeffs)
  for (int i = tid; i < AA * RA; i += stride) {
    int p = i / RA, k = i % RA;
    int a = p & 3;
    float s1 = 0.f, s2 = 0.f;
    for (int r = 0; r < RR; ++r) {
      s1 += coeffs[(r * AA + a) * RA + k];
      s2 += coeffs[(r * AA + a + 4) * RA + k];
    }
    G[i] = (p < 4) ? (s1 + s2) : (s1 - s2);
  }
  // Bh[col][k], col = half*1024 + o*8 + t*4 + j, k = a4*128 + f
  //  E: 0.5*(W[m] + W[m+4]),  O: s*0.5*(W[m]-W[m+4]),  m=(a4+j)&3, s=-1 iff a4+j>=4
  for (int i = tid; i < 2048 * KB; i += stride) {
    int col = i >> 9, k = i & 511;
    int half = col >> 10, c = col & 1023;
    int o = c >> 3, t = (c >> 2) & 1, j = c & 3;
    int a4 = k >> 7, f = k & 127;
    int m = (a4 + j) & 3;
    float w0 = W[((m * TT + t) * OO + o) * FF + f];
    float w4 = W[(((m + 4) * TT + t) * OO + o) * FF + f];
    float v;
    if (half == 0) v = 0.5f * (w0 + w4);
    else {
      v = 0.5f * (w0 - w4);
      if (a4 + j >= 4) v = -v;
    }
    Bh[i] = __float2bfloat16(v);
  }
  if (do_pack) {
    for (int i = tid; i < NN * 120; i += stride) {
      __hip_bfloat16 h = __float2bfloat16(bary_w[i]);
      unsigned wb = *(unsigned short*)&h;
      packb[i] = ((unsigned)bary_idx[i] << 16) | wb;
    }
  }
}

// ---------- S pass (packed, per-slice, 4 features/lane, pk-f32 math) ----------
__global__ __launch_bounds__(256) void s_pass_packed(
    const __hip_bfloat16* __restrict__ meshq,
    const unsigned* __restrict__ packb,
    const float* __restrict__ G,
    __hip_bfloat16* __restrict__ Sout,
    int p) {
  __shared__ unsigned pk_s[32 * 120];
  __shared__ float g_s[AA * RA];
  int tid = threadIdx.x;
  long n0 = (long)blockIdx.x * 32;
  int nnode = (NN - n0 < 32) ? (int)(NN - n0) : 32;
  int nvec = nnode * 30;
  const i32x4* psrc = (const i32x4*)(packb + n0 * 120);
  for (int i = tid; i < nvec; i += 256) {
    i32x4 v = __builtin_nontemporal_load(psrc + i);
    ((i32x4*)pk_s)[i] = v;
  }
  for (int i = tid; i < AA * RA; i += 256) g_s[i] = G[i];
  __syncthreads();

  int g = tid >> 3;
  int fo = tid & 7;
  long n = n0 + g;
  if (n >= NN) return;
  const unsigned* pg = pk_s + g * 120;
  const char* mbase = (const char*)meshq + (long)p * NN * 64 + fo * 8;

  f32x2 accA[AA], accB[AA];
#pragma unroll
  for (int a = 0; a < AA; ++a) {
    accA[a] = (f32x2){0.f, 0.f};
    accB[a] = (f32x2){0.f, 0.f};
  }

#pragma unroll 2
  for (int k = 0; k < RA; ++k) {
    f32x2 sA = (f32x2){0.f, 0.f}, sB = (f32x2){0.f, 0.f};
#pragma unroll
    for (int j = 0; j < 3; ++j) {
      unsigned v = pg[k * 3 + j];
      long row = v >> 16;
      float w = __uint_as_float(v << 16);
      f32x2 wv = (f32x2){w, w};
      u32x2 u = *(const u32x2*)(mbase + row * 64);
      f32x2 lo = (f32x2){__uint_as_float(u[0] << 16),
                         __uint_as_float(u[0] & 0xffff0000u)};
      f32x2 hi = (f32x2){__uint_as_float(u[1] << 16),
                         __uint_as_float(u[1] & 0xffff0000u)};
      sA = pk_fma(wv, lo, sA);
      sB = pk_fma(wv, hi, sB);
    }
#pragma unroll
    for (int a = 0; a < AA; ++a) {
      float cc = g_s[a * RA + k];
      f32x2 cv = (f32x2){cc, cc};
      accA[a] = pk_fma(cv, sA, accA[a]);
      accB[a] = pk_fma(cv, sB, accB[a]);
    }
  }

  long base = n * KDIM + p * 32 + fo * 4;
#pragma unroll
  for (int a = 0; a < AA; ++a) {
    __hip_bfloat16 h0 = __float2bfloat16(accA[a][0]);
    __hip_bfloat16 h1 = __float2bfloat16(accA[a][1]);
    __hip_bfloat16 h2 = __float2bfloat16(accB[a][0]);
    __hip_bfloat16 h3 = __float2bfloat16(accB[a][1]);
    unsigned w0 = (unsigned)*(unsigned short*)&h0 |
                  ((unsigned)*(unsigned short*)&h1 << 16);
    unsigned w1 = (unsigned)*(unsigned short*)&h2 |
                  ((unsigned)*(unsigned short*)&h3 << 16);
    u32x2 st = (u32x2){w0, w1};
    __builtin_nontemporal_store(st, (u32x2*)(Sout + base + a * FF));
  }
}

// ---------- S pass (legacy fallback, per-slice) ----------
__global__ __launch_bounds__(256) void s_pass_kernel(
    const __hip_bfloat16* __restrict__ meshq,
    const float* __restrict__ bary_w,
    const int* __restrict__ bary_idx,
    const float* __restrict__ G,
    __hip_bfloat16* __restrict__ Sout,
    int p) {
  __shared__ float w_s[16 * 120];
  __shared__ int i_s[16 * 120];
  __shared__ float g_s[AA * RA];
  int tid = threadIdx.x;
  long n0 = (long)blockIdx.x * 16;
  const f32x4* wsrc = (const f32x4*)(bary_w + n0 * 120);
  const i32x4* isrc = (const i32x4*)(bary_idx + n0 * 120);
  for (int i = tid; i < 480; i += 256) {
    f32x4 wv = __builtin_nontemporal_load(wsrc + i);
    ((f32x4*)w_s)[i] = wv;
    i32x4 iv = __builtin_nontemporal_load(isrc + i);
    ((i32x4*)i_s)[i] = iv;
  }
  for (int i = tid; i < AA * RA; i += 256) g_s[i] = G[i];
  __syncthreads();
  int g = tid >> 4;
  int fo = tid & 15;
  long n = n0 + g;
  const float* wg = w_s + g * 120;
  const int* ig = i_s + g * 120;
  const char* mbase = (const char*)meshq + (long)p * NN * 64 + fo * 4;
  float sx_acc[AA], sy_acc[AA];
#pragma unroll
  for (int a = 0; a < AA; ++a) { sx_acc[a] = 0.f; sy_acc[a] = 0.f; }
#pragma unroll 2
  for (int k = 0; k < RA; ++k) {
    float sx = 0.f, sy = 0.f;
#pragma unroll
    for (int j = 0; j < 3; ++j) {
      int row = ig[k * 3 + j];
      unsigned u = *(const unsigned*)(mbase + (long)row * 64);
      float w = wg[k * 3 + j];
      sx += w * __uint_as_float(u << 16);
      sy += w * __uint_as_float(u & 0xffff0000u);
    }
#pragma unroll
    for (int a = 0; a < AA; ++a) {
      float c = g_s[a * RA + k];
      sx_acc[a] += c * sx;
      sy_acc[a] += c * sy;
    }
  }
  long base = n * KDIM + p * 32 + fo * 2;
#pragma unroll
  for (int a = 0; a < AA; ++a) {
    __hip_bfloat16 hx = __float2bfloat16(sx_acc[a]);
    __hip_bfloat16 hy = __float2bfloat16(sy_acc[a]);
    unsigned u = (unsigned)*(unsigned short*)&hx | ((unsigned)*(unsigned short*)&hy << 16);
    __builtin_nontemporal_store(u, (unsigned*)(Sout + base + a * FF));
  }
}

// ---------- GEMM (radix-2, big tile): block = 256 rows x (256E + 256O cols), K=512.
// 512 thr = 8 waves (2M x 4N); per wave 128 rows x 64 cols per half (acc[8][8] f32x4).
// 2 LDS buffers x 64KB (Sp|Sm|BE|BO 16KB each). 1 block/CU. 16 K-steps, vmcnt(0) drain.
// Restores R6-level FLOP/LDS-byte (131/B) at radix FLOP count.
// grid (8, 100): cb = by&3 (col-block = 32 o), mt = (by>>2)*8 + bx (A-share same XCD)
__global__ __launch_bounds__(512, 1) void gemm_kernel(
    const __hip_bfloat16* __restrict__ Sh,
    const __hip_bfloat16* __restrict__ Bh,
    const float* __restrict__ bias,
    float* __restrict__ out) {
  int bx = blockIdx.x;
  int by = blockIdx.y;
  int cb = by & 3;                 // column block 0..3 (32 o values)
  int mt = ((by >> 2) << 3) + bx;  // row tile 0..199
  if (mt >= 196) return;
  int row0 = mt * 256;
  int cE0 = cb * 256;              // E col base; O cols = 1024 + same

  int tid = threadIdx.x;
  int lane = tid & 63;
  int wid = tid >> 6;
  int wave_m = wid >> 2;   // 0..1 (128 rows each)
  int wave_n = wid & 3;    // 0..3 (64 cols each per half)

  // 2 buffers x 64KB: Sp [0,16K) | Sm [16K,32K) | BE [32K,48K) | BO [48K,64K)
  // Epilogue reuses [0, 37376): lout 32 rows x (8 kr x 36 + pad) floats.
  __shared__ __align__(16) char lds[131072];

  long srcSp[2], srcB[2];
  int dstA[2], dstBd[2];
#pragma unroll
  for (int i = 0; i < 2; ++i) {
    int li = i * 512 + tid;
    int r = li >> 2, sp = li & 3;
    int sl = sp ^ ((r >> 1) & 3);
    int rowA = row0 + r;
    if (rowA >= NN) rowA = NN - 1;
    srcSp[i] = (long)rowA * KDIM + sl * 8;
    dstA[i] = li * 16;
    srcB[i] = (long)(cE0 + r) * KB + sl * 8;
    dstBd[i] = 32768 + li * 16;
  }
  int offA[8], offB[4];
#pragma unroll
  for (int m = 0; m < 8; ++m) {
    int r = wave_m * 128 + m * 16 + (lane & 15);
    int phys = (lane >> 4) ^ ((r >> 1) & 3);
    offA[m] = r * 64 + phys * 16;
  }
#pragma unroll
  for (int n = 0; n < 4; ++n) {
    int c = wave_n * 64 + n * 16 + (lane & 15);
    int phys = (lane >> 4) ^ ((c >> 1) & 3);
    offB[n] = 32768 + c * 64 + phys * 16;
  }

  f32x4 acc[8][8];  // [m][n<4: E, n>=4: O]
#pragma unroll
  for (int m = 0; m < 8; ++m)
#pragma unroll
    for (int q = 0; q < 8; ++q) acc[m][q] = (f32x4){0.f, 0.f, 0.f, 0.f};

  // stage step T into buffer T&1: Sp, Sm, BE, BO (8 loads/thread)
#define STAGE(T)                                                              \
  {                                                                           \
    char* base_ = lds + ((T) & 1) * 65536;                                    \
    long k0_ = (long)(T) * 32;                                                \
    _Pragma("unroll") for (int i_ = 0; i_ < 2; ++i_)                          \
        gload_lds16(Sh + srcSp[i_] + k0_, base_ + dstA[i_]);                  \
    _Pragma("unroll") for (int i_ = 0; i_ < 2; ++i_)                          \
        gload_lds16(Sh + srcSp[i_] + 512 + k0_, base_ + 16384 + dstA[i_]);    \
    _Pragma("unroll") for (int i_ = 0; i_ < 2; ++i_)                          \
        gload_lds16(Bh + srcB[i_] + k0_, base_ + dstBd[i_]);                  \
    _Pragma("unroll") for (int i_ = 0; i_ < 2; ++i_)                          \
        gload_lds16(Bh + srcB[i_] + (long)1024 * KB + k0_,                    \
                    base_ + 16384 + dstBd[i_]);                               \
  }

#define GSTEP(STP, DOSTAGE)                                                   \
  {                                                                           \
    const char* cbuf = lds + ((STP) & 1) * 65536;                             \
    asm volatile("s_waitcnt vmcnt(0)" ::: "memory");                          \
    __builtin_amdgcn_sched_barrier(0);                                        \
    __builtin_amdgcn_s_barrier();                                             \
    __builtin_amdgcn_sched_barrier(0);                                        \
    if (DOSTAGE) STAGE((STP) + 1)                                             \
    __builtin_amdgcn_sched_barrier(0);                                        \
    short8 aE[8], aO[8], bE[4], bO[4];                                        \
    _Pragma("unroll") for (int n_ = 0; n_ < 4; ++n_) {                        \
      bE[n_] = *(const short8*)(cbuf + offB[n_]);                             \
      bO[n_] = *(const short8*)(cbuf + offB[n_] + 16384);                     \
    }                                                                         \
    _Pragma("unroll") for (int m_ = 0; m_ < 8; ++m_) {                        \
      aE[m_] = *(const short8*)(cbuf + offA[m_]);                             \
      aO[m_] = *(const short8*)(cbuf + offA[m_] + 16384);                     \
    }                                                                         \
    __builtin_amdgcn_s_setprio(1);                                            \
    _Pragma("unroll") for (int m_ = 0; m_ < 8; ++m_)                          \
        _Pragma("unroll") for (int n_ = 0; n_ < 4; ++n_) {                    \
      acc[m_][n_] = __builtin_amdgcn_mfma_f32_16x16x32_bf16(                  \
          aE[m_], bE[n_], acc[m_][n_], 0, 0, 0);                              \
      acc[m_][n_ + 4] = __builtin_amdgcn_mfma_f32_16x16x32_bf16(              \
          aO[m_], bO[n_], acc[m_][n_ + 4], 0, 0, 0);                          \
    }                                                                         \
    __builtin_amdgcn_s_setprio(0);                                            \
    __builtin_amdgcn_sched_barrier(0);                                        \
  }

  STAGE(0)
  GSTEP(0, 1)  GSTEP(1, 1)  GSTEP(2, 1)  GSTEP(3, 1)
  GSTEP(4, 1)  GSTEP(5, 1)  GSTEP(6, 1)  GSTEP(7, 1)
  GSTEP(8, 1)  GSTEP(9, 1)  GSTEP(10, 1) GSTEP(11, 1)
  GSTEP(12, 1) GSTEP(13, 1) GSTEP(14, 1) GSTEP(15, 0)

  // ---- epilogue (per 16-row m-chunk): z = E+-O, +40*bias, relu, t-sum shfl_xor(4),
  //      LDS-stage 32 rows x 8 kr x 32 o (stride 292/36, float4-aligned), then
  //      coalesced 128B-per-(row,kr) float4 stores ----
  float* lout = (float*)lds;
  int c = lane & 15;
  int t = (c >> 2) & 1;
  int j = c & 3;
  int hi = lane >> 4;
  float bq[4];
#pragma unroll
  for (int n = 0; n < 4; ++n) {
    int o_l = wave_n * 8 + n * 2 + (c >> 3);
    bq[n] = 40.f * bias[t * OO + cb * 32 + o_l];
  }
#pragma unroll
  for (int m = 0; m < 8; ++m) {
    __syncthreads();  // lout free (prev copy done / K-loop reads done)
#pragma unroll
    for (int n = 0; n < 4; ++n) {
      int o_l = wave_n * 8 + n * 2 + (c >> 3);
#pragma unroll
      for (int i = 0; i < 4; ++i) {
        float zE = acc[m][n][i];
        float zO = acc[m][n + 4][i];
        float rlo = fmaxf(zE + zO + bq[n], 0.f);
        float rhi = fmaxf(zE - zO + bq[n], 0.f);
        rlo += __shfl_xor(rlo, 4);
        rhi += __shfl_xor(rhi, 4);
        if (!(lane & 4)) {
          int cl = wave_m * 16 + hi * 4 + i;
          lout[cl * 292 + j * 36 + o_l] = rlo;
          lout[cl * 292 + (j + 4) * 36 + o_l] = rhi;
        }
      }
    }
    __syncthreads();
    // copy chunk: 32 rows x 8 kr x 8 float4 = 2048 float4, 512 thr -> 4 iters
#pragma unroll
    for (int it = 0; it < 4; ++it) {
      int gi = it * 512 + tid;
      int cl = gi >> 6;
      int rem = gi & 63;
      int kr = rem >> 3, q = rem & 7;
      int grow = row0 + (cl >> 4) * 128 + m * 16 + (cl & 15);
      if (grow < NN) {
        f32x4 v = *(const f32x4*)(lout + cl * 292 + kr * 36 + q * 4);
        long gaddr = (long)grow * 1024 + kr * 128 + cb * 32 + q * 4;
        __builtin_nontemporal_store(v, (f32x4*)(out + gaddr));
      }
    }
  }
}

extern "C" void kernel_launch(void* const* d_in, const int* in_sizes, int n_in,
                              void* d_out, int out_size, void* d_ws, size_t ws_size,
                              hipStream_t stream) {
  const float* mesh   = (const float*)d_in[0];
  const float* bary_w = (const float*)d_in[1];
  const float* W      = (const float*)d_in[2];
  const float* bias   = (const float*)d_in[3];
  const float* coeffs = (const float*)d_in[4];
  const int* bidx     = (const int*)d_in[5];
  float* out = (float*)d_out;
  char* ws = (char*)d_ws;

  __hip_bfloat16* meshq = (__hip_bfloat16*)ws;                    // 12,800,000 B
  float* G              = (float*)(ws + 12800000);                // 1,280 B
  __hip_bfloat16* Bh    = (__hip_bfloat16*)(ws + 12801280);       // 2,097,152 B (slot 4MB)
  __hip_bfloat16* Smat  = (__hip_bfloat16*)(ws + 16995584);       // 102,400,000 B
  unsigned* packb       = (unsigned*)(ws + 119395584);            // 24,000,000 B

  int do_pack = (ws_size >= 143395584UL) ? 1 : 0;

  prep_kernel<<<dim3(2048), dim3(256), 0, stream>>>(mesh, coeffs, W, bary_w, bidx,
                                                    meshq, G, Bh, packb, do_pack);
  if (do_pack) {
    for (int p = 0; p < 4; ++p)
      s_pass_packed<<<dim3(1563), dim3(256), 0, stream>>>(meshq, packb, G, Smat, p);
  } else {
    for (int p = 0; p < 4; ++p)
      s_pass_kernel<<<dim3(3125), dim3(256), 0, stream>>>(meshq, bary_w, bidx, G, Smat, p);
  }
  gemm_kernel<<<dim3(8, 100), dim3(512), 0, stream>>>(Smat, Bh, bias, out);
}

// Round 14
// 405.856 us; speedup vs baseline: 3.4602x; 3.4602x over previous
//
#include <hip/hip_runtime.h>
#include <hip/hip_bf16.h>
#include <stdint.h>

#define NN 50000
#define RR 5
#define AA 8
#define FF 128
#define TT 2
#define OO 128
#define KDIM 1024   // 8 planes * F
#define KB 512      // K per half (E or O)
#define RA 40       // R*A

typedef __attribute__((ext_vector_type(8))) short short8;
typedef __attribute__((ext_vector_type(4))) float f32x4;
typedef __attribute__((ext_vector_type(2))) float f32x2;
typedef __attribute__((ext_vector_type(4))) int i32x4;
typedef __attribute__((ext_vector_type(2))) unsigned u32x2;

#if __has_builtin(__builtin_elementwise_fma)
__device__ inline f32x2 pk_fma(f32x2 a, f32x2 b, f32x2 c) {
  return __builtin_elementwise_fma(a, b, c);
}
#else
__device__ inline f32x2 pk_fma(f32x2 a, f32x2 b, f32x2 c) {
  f32x2 d;
  asm("v_pk_fma_f32 %0, %1, %2, %3" : "=v"(d) : "v"(a), "v"(b), "v"(c));
  return d;
}
#endif

__device__ inline void gload_lds16(const void* g, void* l) {
  __builtin_amdgcn_global_load_lds(
      (const __attribute__((address_space(1))) unsigned int*)g,
      (__attribute__((address_space(3))) unsigned int*)l, 16, 0, 0);
}

// ---------- prep: mesh->bf16 sliced, G (radix-2 mix), Bh (E/O weights), packed bary --
__global__ void prep_kernel(const float* __restrict__ mesh,
                            const float* __restrict__ coeffs,
                            const float* __restrict__ W,
                            const float* __restrict__ bary_w,
                            const int* __restrict__ bary_idx,
                            __hip_bfloat16* __restrict__ meshq,  // [4][N][32]
                            float* __restrict__ G,               // [8][40]
                            __hip_bfloat16* __restrict__ Bh,     // [2048][512]
                            unsigned* __restrict__ packb,
                            int do_pack) {
  int tid = blockIdx.x * blockDim.x + threadIdx.x;
  int stride = gridDim.x * blockDim.x;
  for (int i = tid; i < NN * FF; i += stride) {
    int n = i >> 7, f = i & 127;
    int p = f >> 5, fo = f & 31;
    meshq[((long)p * NN + n) * 32 + fo] = __float2bfloat16(mesh[i]);
  }
  // G[p][k]: p<4 -> C2[p]+C2[p+4];  p>=4 -> C2[p-4]-C2[p]   (C2 = sum_r coeffs)
  for (int i = tid; i < AA * RA; i += stride) {
    int p = i / RA, k = i % RA;
    int a = p & 3;
    float s1 = 0.f, s2 = 0.f;
    for (int r = 0; r < RR; ++r) {
      s1 += coeffs[(r * AA + a) * RA + k];
      s2 += coeffs[(r * AA + a + 4) * RA + k];
    }
    G[i] = (p < 4) ? (s1 + s2) : (s1 - s2);
  }
  // Bh[col][k], col = half*1024 + o*8 + t*4 + j, k = a4*128 + f
  //  E: 0.5*(W[m] + W[m+4]),  O: s*0.5*(W[m]-W[m+4]),  m=(a4+j)&3, s=-1 iff a4+j>=4
  for (int i = tid; i < 2048 * KB; i += stride) {
    int col = i >> 9, k = i & 511;
    int half = col >> 10, c = col & 1023;
    int o = c >> 3, t = (c >> 2) & 1, j = c & 3;
    int a4 = k >> 7, f = k & 127;
    int m = (a4 + j) & 3;
    float w0 = W[((m * TT + t) * OO + o) * FF + f];
    float w4 = W[(((m + 4) * TT + t) * OO + o) * FF + f];
    float v;
    if (half == 0) v = 0.5f * (w0 + w4);
    else {
      v = 0.5f * (w0 - w4);
      if (a4 + j >= 4) v = -v;
    }
    Bh[i] = __float2bfloat16(v);
  }
  if (do_pack) {
    for (int i = tid; i < NN * 120; i += stride) {
      __hip_bfloat16 h = __float2bfloat16(bary_w[i]);
      unsigned wb = *(unsigned short*)&h;
      packb[i] = ((unsigned)bary_idx[i] << 16) | wb;
    }
  }
}

// ---------- S pass (packed, per-slice, 4 features/lane, pk-f32 math) ----------
__global__ __launch_bounds__(256) void s_pass_packed(
    const __hip_bfloat16* __restrict__ meshq,
    const unsigned* __restrict__ packb,
    const float* __restrict__ G,
    __hip_bfloat16* __restrict__ Sout,
    int p) {
  __shared__ unsigned pk_s[32 * 120];
  __shared__ float g_s[AA * RA];
  int tid = threadIdx.x;
  long n0 = (long)blockIdx.x * 32;
  int nnode = (NN - n0 < 32) ? (int)(NN - n0) : 32;
  int nvec = nnode * 30;
  const i32x4* psrc = (const i32x4*)(packb + n0 * 120);
  for (int i = tid; i < nvec; i += 256) {
    i32x4 v = __builtin_nontemporal_load(psrc + i);
    ((i32x4*)pk_s)[i] = v;
  }
  for (int i = tid; i < AA * RA; i += 256) g_s[i] = G[i];
  __syncthreads();

  int g = tid >> 3;
  int fo = tid & 7;
  long n = n0 + g;
  if (n >= NN) return;
  const unsigned* pg = pk_s + g * 120;
  const char* mbase = (const char*)meshq + (long)p * NN * 64 + fo * 8;

  f32x2 accA[AA], accB[AA];
#pragma unroll
  for (int a = 0; a < AA; ++a) {
    accA[a] = (f32x2){0.f, 0.f};
    accB[a] = (f32x2){0.f, 0.f};
  }

#pragma unroll 2
  for (int k = 0; k < RA; ++k) {
    f32x2 sA = (f32x2){0.f, 0.f}, sB = (f32x2){0.f, 0.f};
#pragma unroll
    for (int j = 0; j < 3; ++j) {
      unsigned v = pg[k * 3 + j];
      long row = v >> 16;
      float w = __uint_as_float(v << 16);
      f32x2 wv = (f32x2){w, w};
      u32x2 u = *(const u32x2*)(mbase + row * 64);
      f32x2 lo = (f32x2){__uint_as_float(u[0] << 16),
                         __uint_as_float(u[0] & 0xffff0000u)};
      f32x2 hi = (f32x2){__uint_as_float(u[1] << 16),
                         __uint_as_float(u[1] & 0xffff0000u)};
      sA = pk_fma(wv, lo, sA);
      sB = pk_fma(wv, hi, sB);
    }
#pragma unroll
    for (int a = 0; a < AA; ++a) {
      float cc = g_s[a * RA + k];
      f32x2 cv = (f32x2){cc, cc};
      accA[a] = pk_fma(cv, sA, accA[a]);
      accB[a] = pk_fma(cv, sB, accB[a]);
    }
  }

  long base = n * KDIM + p * 32 + fo * 4;
#pragma unroll
  for (int a = 0; a < AA; ++a) {
    __hip_bfloat16 h0 = __float2bfloat16(accA[a][0]);
    __hip_bfloat16 h1 = __float2bfloat16(accA[a][1]);
    __hip_bfloat16 h2 = __float2bfloat16(accB[a][0]);
    __hip_bfloat16 h3 = __float2bfloat16(accB[a][1]);
    unsigned w0 = (unsigned)*(unsigned short*)&h0 |
                  ((unsigned)*(unsigned short*)&h1 << 16);
    unsigned w1 = (unsigned)*(unsigned short*)&h2 |
                  ((unsigned)*(unsigned short*)&h3 << 16);
    u32x2 st = (u32x2){w0, w1};
    __builtin_nontemporal_store(st, (u32x2*)(Sout + base + a * FF));
  }
}

// ---------- S pass (legacy fallback, per-slice) ----------
__global__ __launch_bounds__(256) void s_pass_kernel(
    const __hip_bfloat16* __restrict__ meshq,
    const float* __restrict__ bary_w,
    const int* __restrict__ bary_idx,
    const float* __restrict__ G,
    __hip_bfloat16* __restrict__ Sout,
    int p) {
  __shared__ float w_s[16 * 120];
  __shared__ int i_s[16 * 120];
  __shared__ float g_s[AA * RA];
  int tid = threadIdx.x;
  long n0 = (long)blockIdx.x * 16;
  const f32x4* wsrc = (const f32x4*)(bary_w + n0 * 120);
  const i32x4* isrc = (const i32x4*)(bary_idx + n0 * 120);
  for (int i = tid; i < 480; i += 256) {
    f32x4 wv = __builtin_nontemporal_load(wsrc + i);
    ((f32x4*)w_s)[i] = wv;
    i32x4 iv = __builtin_nontemporal_load(isrc + i);
    ((i32x4*)i_s)[i] = iv;
  }
  for (int i = tid; i < AA * RA; i += 256) g_s[i] = G[i];
  __syncthreads();
  int g = tid >> 4;
  int fo = tid & 15;
  long n = n0 + g;
  const float* wg = w_s + g * 120;
  const int* ig = i_s + g * 120;
  const char* mbase = (const char*)meshq + (long)p * NN * 64 + fo * 4;
  float sx_acc[AA], sy_acc[AA];
#pragma unroll
  for (int a = 0; a < AA; ++a) { sx_acc[a] = 0.f; sy_acc[a] = 0.f; }
#pragma unroll 2
  for (int k = 0; k < RA; ++k) {
    float sx = 0.f, sy = 0.f;
#pragma unroll
    for (int j = 0; j < 3; ++j) {
      int row = ig[k * 3 + j];
      unsigned u = *(const unsigned*)(mbase + (long)row * 64);
      float w = wg[k * 3 + j];
      sx += w * __uint_as_float(u << 16);
      sy += w * __uint_as_float(u & 0xffff0000u);
    }
#pragma unroll
    for (int a = 0; a < AA; ++a) {
      float c = g_s[a * RA + k];
      sx_acc[a] += c * sx;
      sy_acc[a] += c * sy;
    }
  }
  long base = n * KDIM + p * 32 + fo * 2;
#pragma unroll
  for (int a = 0; a < AA; ++a) {
    __hip_bfloat16 hx = __float2bfloat16(sx_acc[a]);
    __hip_bfloat16 hy = __float2bfloat16(sy_acc[a]);
    unsigned u = (unsigned)*(unsigned short*)&hx | ((unsigned)*(unsigned short*)&hy << 16);
    __builtin_nontemporal_store(u, (unsigned*)(Sout + base + a * FF));
  }
}

// ---------- GEMM (radix-2, wave-split E/O): block = 256 rows x 128 cols-per-half.
// 8 waves: wid 0-3 compute E (Sp@BE), wid 4-7 compute O (Sm@BO) — each wave is an
// R6-structure GEMM wave: m=8, n=4, 12 ds_reads / 32 MFMAs, acc[8][4] (~210 VGPR,
// fits 2-waves/SIMD cap). 3 x 48KB LDS buffers, counted vmcnt(6) (R6 schedule).
// Epilogue: E-acc -> LDS handoff -> O-waves merge (E+-O, bias, relu, t-shfl) -> lout
// -> coalesced copy. grid (8, 200): cb = by&7, mt = (by>>3)*8 + bx (XCD A-share).
__global__ __launch_bounds__(512, 1) void gemm_kernel(
    const __hip_bfloat16* __restrict__ Sh,
    const __hip_bfloat16* __restrict__ Bh,
    const float* __restrict__ bias,
    float* __restrict__ out) {
  int bx = blockIdx.x;
  int by = blockIdx.y;
  int cb = by & 7;                 // column block 0..7 (16 o values)
  int mt = ((by >> 3) << 3) + bx;  // row tile
  if (mt >= 196) return;
  int row0 = mt * 256;
  int cE0 = cb * 128;              // col base within the 1024-col half

  int tid = threadIdx.x;
  int lane = tid & 63;
  int wid = tid >> 6;
  int half = wid >> 2;        // 0 = E, 1 = O
  int wm = (wid >> 1) & 1;    // wave row group (128 rows)
  int wn = wid & 1;           // wave col group (64 cols)

  // 3 buffers x 48KB: Sp [0,16K) | Sm [16K,32K) | BE [32K,40K) | BO [40K,48K)
  // Epilogue reuse: estg 16KB at 0; lout 37376B at 16384.
  __shared__ __align__(16) char lds[147456];

  long srcSp[2];
  int dstA[2];
#pragma unroll
  for (int i = 0; i < 2; ++i) {
    int li = i * 512 + tid;
    int r = li >> 2, sp = li & 3;
    int sl = sp ^ ((r >> 1) & 3);
    int rowA = row0 + r;
    if (rowA >= NN) rowA = NN - 1;
    srcSp[i] = (long)rowA * KDIM + sl * 8;
    dstA[i] = li * 16;
  }
  long srcB;
  int dstB;
  {
    int r = tid >> 2, sp = tid & 3;
    int sl = sp ^ ((r >> 1) & 3);
    srcB = (long)(cE0 + r) * KB + sl * 8;
    dstB = 32768 + tid * 16;
  }

  // fragment offsets (include E/O half select — no divergence in the K-loop)
  int offA[8], offB[4];
#pragma unroll
  for (int m = 0; m < 8; ++m) {
    int r = wm * 128 + m * 16 + (lane & 15);
    int phys = (lane >> 4) ^ ((r >> 1) & 3);
    offA[m] = half * 16384 + r * 64 + phys * 16;
  }
#pragma unroll
  for (int n = 0; n < 4; ++n) {
    int c = wn * 64 + n * 16 + (lane & 15);
    int phys = (lane >> 4) ^ ((c >> 1) & 3);
    offB[n] = 32768 + half * 8192 + c * 64 + phys * 16;
  }

  f32x4 acc[8][4];
#pragma unroll
  for (int m = 0; m < 8; ++m)
#pragma unroll
    for (int n = 0; n < 4; ++n) acc[m][n] = (f32x4){0.f, 0.f, 0.f, 0.f};

  // stage step T into buffer T%3 (6 loads/thread: Sp x2, Sm x2, BE, BO)
#define STAGE(T)                                                              \
  {                                                                           \
    char* base_ = lds + ((T) % 3) * 49152;                                    \
    long k0_ = (long)(T) * 32;                                                \
    _Pragma("unroll") for (int i_ = 0; i_ < 2; ++i_)                          \
        gload_lds16(Sh + srcSp[i_] + k0_, base_ + dstA[i_]);                  \
    _Pragma("unroll") for (int i_ = 0; i_ < 2; ++i_)                          \
        gload_lds16(Sh + srcSp[i_] + 512 + k0_, base_ + 16384 + dstA[i_]);    \
    gload_lds16(Bh + srcB + k0_, base_ + dstB);                               \
    gload_lds16(Bh + srcB + (long)1024 * KB + k0_, base_ + 8192 + dstB);      \
  }

#define GSTEP(STP, VMSTR, DOSTAGE)                                           \
  {                                                                          \
    const char* cbuf = lds + ((STP) % 3) * 49152;                            \
    asm volatile("s_waitcnt " VMSTR ::: "memory");                           \
    __builtin_amdgcn_sched_barrier(0);                                       \
    __builtin_amdgcn_s_barrier();                                            \
    __builtin_amdgcn_sched_barrier(0);                                       \
    short8 aF[8], bF[4];                                                     \
    _Pragma("unroll") for (int n_ = 0; n_ < 4; ++n_)                         \
        bF[n_] = *(const short8*)(cbuf + offB[n_]);                          \
    _Pragma("unroll") for (int m_ = 0; m_ < 8; ++m_)                         \
        aF[m_] = *(const short8*)(cbuf + offA[m_]);                          \
    if (DOSTAGE) STAGE((STP) + 2)                                            \
    __builtin_amdgcn_s_setprio(1);                                           \
    _Pragma("unroll") for (int m_ = 0; m_ < 8; ++m_)                         \
        _Pragma("unroll") for (int n_ = 0; n_ < 4; ++n_)                     \
            acc[m_][n_] = __builtin_amdgcn_mfma_f32_16x16x32_bf16(           \
                aF[m_], bF[n_], acc[m_][n_], 0, 0, 0);                       \
    __builtin_amdgcn_s_setprio(0);                                           \
    __builtin_amdgcn_sched_barrier(0);                                       \
  }

  STAGE(0) STAGE(1)
  GSTEP(0, "vmcnt(6)", 1)
  GSTEP(1, "vmcnt(6)", 1)
  GSTEP(2, "vmcnt(6)", 1)
  GSTEP(3, "vmcnt(6)", 1)
  GSTEP(4, "vmcnt(6)", 1)
  GSTEP(5, "vmcnt(6)", 1)
  GSTEP(6, "vmcnt(6)", 1)
  GSTEP(7, "vmcnt(6)", 1)
  GSTEP(8, "vmcnt(6)", 1)
  GSTEP(9, "vmcnt(6)", 1)
  GSTEP(10, "vmcnt(6)", 1)
  GSTEP(11, "vmcnt(6)", 1)
  GSTEP(12, "vmcnt(6)", 1)
  GSTEP(13, "vmcnt(6)", 1)
  GSTEP(14, "vmcnt(6)", 0)
  GSTEP(15, "vmcnt(0)", 0)

  // ---- epilogue per 16-row m-chunk:
  // E-waves stage acc -> estg; O-waves merge (E+O -> kr=j, E-O -> kr=j+4),
  // +40*bias, relu, t-sum shfl_xor(4) -> lout; all copy lout -> out coalesced.
  float* estg = (float*)lds;
  float* lout = (float*)(lds + 16384);
  int c = lane & 15;
  int t = (c >> 2) & 1;
  int j = c & 3;
  int hi = lane >> 4;
  float bq[4];
#pragma unroll
  for (int n = 0; n < 4; ++n) {
    int o_l = wn * 8 + n * 2 + (c >> 3);
    bq[n] = 40.f * bias[t * OO + cb * 16 + o_l];
  }
#pragma unroll
  for (int m = 0; m < 8; ++m) {
    __syncthreads();  // estg/lout free
    if (half == 0) {
#pragma unroll
      for (int n = 0; n < 4; ++n)
        *(f32x4*)(estg + ((n * 4 + wid) * 64 + lane) * 4) = acc[m][n];
    }
    __syncthreads();
    if (half == 1) {
      int widE = wid - 4;
#pragma unroll
      for (int n = 0; n < 4; ++n) {
        f32x4 e = *(const f32x4*)(estg + ((n * 4 + widE) * 64 + lane) * 4);
        int o_l = wn * 8 + n * 2 + (c >> 3);
#pragma unroll
        for (int i = 0; i < 4; ++i) {
          float rlo = fmaxf(e[i] + acc[m][n][i] + bq[n], 0.f);
          float rhi = fmaxf(e[i] - acc[m][n][i] + bq[n], 0.f);
          rlo += __shfl_xor(rlo, 4);
          rhi += __shfl_xor(rhi, 4);
          if (!(lane & 4)) {
            int cl = wm * 16 + hi * 4 + i;
            lout[cl * 292 + j * 36 + o_l] = rlo;
            lout[cl * 292 + (j + 4) * 36 + o_l] = rhi;
          }
        }
      }
    }
    __syncthreads();
    // copy chunk: 32 rows x 8 kr x 4 float4 = 1024 float4, 512 thr -> 2 iters
#pragma unroll
    for (int it = 0; it < 2; ++it) {
      int gi = it * 512 + tid;
      int cl = gi >> 5;
      int rem = gi & 31;
      int kr = rem >> 2, q = rem & 3;
      int grow = row0 + (cl >> 4) * 128 + m * 16 + (cl & 15);
      if (grow < NN) {
        f32x4 v = *(const f32x4*)(lout + cl * 292 + kr * 36 + q * 4);
        long gaddr = (long)grow * 1024 + kr * 128 + cb * 16 + q * 4;
        __builtin_nontemporal_store(v, (f32x4*)(out + gaddr));
      }
    }
  }
}

extern "C" void kernel_launch(void* const* d_in, const int* in_sizes, int n_in,
                              void* d_out, int out_size, void* d_ws, size_t ws_size,
                              hipStream_t stream) {
  const float* mesh   = (const float*)d_in[0];
  const float* bary_w = (const float*)d_in[1];
  const float* W      = (const float*)d_in[2];
  const float* bias   = (const float*)d_in[3];
  const float* coeffs = (const float*)d_in[4];
  const int* bidx     = (const int*)d_in[5];
  float* out = (float*)d_out;
  char* ws = (char*)d_ws;

  __hip_bfloat16* meshq = (__hip_bfloat16*)ws;                    // 12,800,000 B
  float* G              = (float*)(ws + 12800000);                // 1,280 B
  __hip_bfloat16* Bh    = (__hip_bfloat16*)(ws + 12801280);       // 2,097,152 B (slot 4MB)
  __hip_bfloat16* Smat  = (__hip_bfloat16*)(ws + 16995584);       // 102,400,000 B
  unsigned* packb       = (unsigned*)(ws + 119395584);            // 24,000,000 B

  int do_pack = (ws_size >= 143395584UL) ? 1 : 0;

  prep_kernel<<<dim3(2048), dim3(256), 0, stream>>>(mesh, coeffs, W, bary_w, bidx,
                                                    meshq, G, Bh, packb, do_pack);
  if (do_pack) {
    for (int p = 0; p < 4; ++p)
      s_pass_packed<<<dim3(1563), dim3(256), 0, stream>>>(meshq, packb, G, Smat, p);
  } else {
    for (int p = 0; p < 4; ++p)
      s_pass_kernel<<<dim3(3125), dim3(256), 0, stream>>>(meshq, bary_w, bidx, G, Smat, p);
  }
  gemm_kernel<<<dim3(8, 200), dim3(512), 0, stream>>>(Smat, Bh, bias, out);
}

// Round 15
// 395.755 us; speedup vs baseline: 3.5485x; 1.0255x over previous
//
#include <hip/hip_runtime.h>
#include <hip/hip_bf16.h>
#include <stdint.h>

#define NN 50000
#define RR 5
#define AA 8
#define FF 128
#define TT 2
#define OO 128
#define KDIM 1024   // 8 planes * F
#define KB 512      // K per half (E or O)
#define RA 40       // R*A

typedef __attribute__((ext_vector_type(8))) short short8;
typedef __attribute__((ext_vector_type(4))) float f32x4;
typedef __attribute__((ext_vector_type(2))) float f32x2;
typedef __attribute__((ext_vector_type(4))) int i32x4;
typedef __attribute__((ext_vector_type(2))) unsigned u32x2;

#if __has_builtin(__builtin_elementwise_fma)
__device__ inline f32x2 pk_fma(f32x2 a, f32x2 b, f32x2 c) {
  return __builtin_elementwise_fma(a, b, c);
}
#else
__device__ inline f32x2 pk_fma(f32x2 a, f32x2 b, f32x2 c) {
  f32x2 d;
  asm("v_pk_fma_f32 %0, %1, %2, %3" : "=v"(d) : "v"(a), "v"(b), "v"(c));
  return d;
}
#endif

__device__ inline void gload_lds16(const void* g, void* l) {
  __builtin_amdgcn_global_load_lds(
      (const __attribute__((address_space(1))) unsigned int*)g,
      (__attribute__((address_space(3))) unsigned int*)l, 16, 0, 0);
}

// ---------- prep: mesh->bf16 sliced, G (radix-2 mix), Bh (E/O weights), packed bary --
__global__ void prep_kernel(const float* __restrict__ mesh,
                            const float* __restrict__ coeffs,
                            const float* __restrict__ W,
                            const float* __restrict__ bary_w,
                            const int* __restrict__ bary_idx,
                            __hip_bfloat16* __restrict__ meshq,  // [4][N][32]
                            float* __restrict__ G,               // [8][40]
                            __hip_bfloat16* __restrict__ Bh,     // [2048][512]
                            unsigned* __restrict__ packb,
                            int do_pack) {
  int tid = blockIdx.x * blockDim.x + threadIdx.x;
  int stride = gridDim.x * blockDim.x;
  for (int i = tid; i < NN * FF; i += stride) {
    int n = i >> 7, f = i & 127;
    int p = f >> 5, fo = f & 31;
    meshq[((long)p * NN + n) * 32 + fo] = __float2bfloat16(mesh[i]);
  }
  // G[p][k]: p<4 -> C2[p]+C2[p+4];  p>=4 -> C2[p-4]-C2[p]   (C2 = sum_r coeffs)
  for (int i = tid; i < AA * RA; i += stride) {
    int p = i / RA, k = i % RA;
    int a = p & 3;
    float s1 = 0.f, s2 = 0.f;
    for (int r = 0; r < RR; ++r) {
      s1 += coeffs[(r * AA + a) * RA + k];
      s2 += coeffs[(r * AA + a + 4) * RA + k];
    }
    G[i] = (p < 4) ? (s1 + s2) : (s1 - s2);
  }
  // Bh[col][k], col = half*1024 + o*8 + t*4 + j, k = a4*128 + f
  //  E: 0.5*(W[m] + W[m+4]),  O: s*0.5*(W[m]-W[m+4]),  m=(a4+j)&3, s=-1 iff a4+j>=4
  for (int i = tid; i < 2048 * KB; i += stride) {
    int col = i >> 9, k = i & 511;
    int half = col >> 10, c = col & 1023;
    int o = c >> 3, t = (c >> 2) & 1, j = c & 3;
    int a4 = k >> 7, f = k & 127;
    int m = (a4 + j) & 3;
    float w0 = W[((m * TT + t) * OO + o) * FF + f];
    float w4 = W[(((m + 4) * TT + t) * OO + o) * FF + f];
    float v;
    if (half == 0) v = 0.5f * (w0 + w4);
    else {
      v = 0.5f * (w0 - w4);
      if (a4 + j >= 4) v = -v;
    }
    Bh[i] = __float2bfloat16(v);
  }
  if (do_pack) {
    for (int i = tid; i < NN * 120; i += stride) {
      __hip_bfloat16 h = __float2bfloat16(bary_w[i]);
      unsigned wb = *(unsigned short*)&h;
      packb[i] = ((unsigned)bary_idx[i] << 16) | wb;
    }
  }
}

// ---------- S pass (packed, per-slice, batch-prefetch): 4 features/lane ----------
// 32 nodes x 8 lanes; k-loop split into 5 batches of 8 k's; each batch issues 24
// independent 8B gathers into registers BEFORE the FMAs -> ~24 loads in flight
// (vs ~6 with unroll-2) to hide the ~200cyc L2 latency. Per-slice launches keep
// the gather set to one 3.2MB slice (per-XCD L2-resident; fusing regresses, R10).
__global__ __launch_bounds__(256) void s_pass_packed(
    const __hip_bfloat16* __restrict__ meshq,
    const unsigned* __restrict__ packb,
    const float* __restrict__ G,
    __hip_bfloat16* __restrict__ Sout,
    int p) {
  __shared__ unsigned pk_s[32 * 120];
  __shared__ float g_s[AA * RA];
  int tid = threadIdx.x;
  long n0 = (long)blockIdx.x * 32;
  int nnode = (NN - n0 < 32) ? (int)(NN - n0) : 32;
  int nvec = nnode * 30;
  const i32x4* psrc = (const i32x4*)(packb + n0 * 120);
  for (int i = tid; i < nvec; i += 256) {
    i32x4 v = __builtin_nontemporal_load(psrc + i);
    ((i32x4*)pk_s)[i] = v;
  }
  for (int i = tid; i < AA * RA; i += 256) g_s[i] = G[i];
  __syncthreads();

  int g = tid >> 3;
  int fo = tid & 7;
  long n = n0 + g;
  if (n >= NN) return;
  const unsigned* pg = pk_s + g * 120;
  const char* mbase = (const char*)meshq + (long)p * NN * 64 + fo * 8;

  f32x2 accA[AA], accB[AA];
#pragma unroll
  for (int a = 0; a < AA; ++a) {
    accA[a] = (f32x2){0.f, 0.f};
    accB[a] = (f32x2){0.f, 0.f};
  }

  for (int kb = 0; kb < 5; ++kb) {  // 5 batches x 8 k
    u32x2 u[24];
    float w[24];
#pragma unroll
    for (int i = 0; i < 24; ++i) {
      unsigned v = pg[kb * 24 + i];
      w[i] = __uint_as_float(v << 16);
      u[i] = *(const u32x2*)(mbase + (long)(v >> 16) * 64);
    }
#pragma unroll
    for (int kk = 0; kk < 8; ++kk) {
      int k = kb * 8 + kk;
      f32x2 sA = (f32x2){0.f, 0.f}, sB = (f32x2){0.f, 0.f};
#pragma unroll
      for (int j = 0; j < 3; ++j) {
        int i = kk * 3 + j;
        f32x2 wv = (f32x2){w[i], w[i]};
        f32x2 lo = (f32x2){__uint_as_float(u[i][0] << 16),
                           __uint_as_float(u[i][0] & 0xffff0000u)};
        f32x2 hi = (f32x2){__uint_as_float(u[i][1] << 16),
                           __uint_as_float(u[i][1] & 0xffff0000u)};
        sA = pk_fma(wv, lo, sA);
        sB = pk_fma(wv, hi, sB);
      }
#pragma unroll
      for (int a = 0; a < AA; ++a) {
        float cc = g_s[a * RA + k];
        f32x2 cv = (f32x2){cc, cc};
        accA[a] = pk_fma(cv, sA, accA[a]);
        accB[a] = pk_fma(cv, sB, accB[a]);
      }
    }
  }

  long base = n * KDIM + p * 32 + fo * 4;
#pragma unroll
  for (int a = 0; a < AA; ++a) {
    __hip_bfloat16 h0 = __float2bfloat16(accA[a][0]);
    __hip_bfloat16 h1 = __float2bfloat16(accA[a][1]);
    __hip_bfloat16 h2 = __float2bfloat16(accB[a][0]);
    __hip_bfloat16 h3 = __float2bfloat16(accB[a][1]);
    unsigned w0 = (unsigned)*(unsigned short*)&h0 |
                  ((unsigned)*(unsigned short*)&h1 << 16);
    unsigned w1 = (unsigned)*(unsigned short*)&h2 |
                  ((unsigned)*(unsigned short*)&h3 << 16);
    u32x2 st = (u32x2){w0, w1};
    __builtin_nontemporal_store(st, (u32x2*)(Sout + base + a * FF));
  }
}

// ---------- S pass (legacy fallback, per-slice) ----------
__global__ __launch_bounds__(256) void s_pass_kernel(
    const __hip_bfloat16* __restrict__ meshq,
    const float* __restrict__ bary_w,
    const int* __restrict__ bary_idx,
    const float* __restrict__ G,
    __hip_bfloat16* __restrict__ Sout,
    int p) {
  __shared__ float w_s[16 * 120];
  __shared__ int i_s[16 * 120];
  __shared__ float g_s[AA * RA];
  int tid = threadIdx.x;
  long n0 = (long)blockIdx.x * 16;
  const f32x4* wsrc = (const f32x4*)(bary_w + n0 * 120);
  const i32x4* isrc = (const i32x4*)(bary_idx + n0 * 120);
  for (int i = tid; i < 480; i += 256) {
    f32x4 wv = __builtin_nontemporal_load(wsrc + i);
    ((f32x4*)w_s)[i] = wv;
    i32x4 iv = __builtin_nontemporal_load(isrc + i);
    ((i32x4*)i_s)[i] = iv;
  }
  for (int i = tid; i < AA * RA; i += 256) g_s[i] = G[i];
  __syncthreads();
  int g = tid >> 4;
  int fo = tid & 15;
  long n = n0 + g;
  const float* wg = w_s + g * 120;
  const int* ig = i_s + g * 120;
  const char* mbase = (const char*)meshq + (long)p * NN * 64 + fo * 4;
  float sx_acc[AA], sy_acc[AA];
#pragma unroll
  for (int a = 0; a < AA; ++a) { sx_acc[a] = 0.f; sy_acc[a] = 0.f; }
#pragma unroll 2
  for (int k = 0; k < RA; ++k) {
    float sx = 0.f, sy = 0.f;
#pragma unroll
    for (int j = 0; j < 3; ++j) {
      int row = ig[k * 3 + j];
      unsigned u = *(const unsigned*)(mbase + (long)row * 64);
      float w = wg[k * 3 + j];
      sx += w * __uint_as_float(u << 16);
      sy += w * __uint_as_float(u & 0xffff0000u);
    }
#pragma unroll
    for (int a = 0; a < AA; ++a) {
      float c = g_s[a * RA + k];
      sx_acc[a] += c * sx;
      sy_acc[a] += c * sy;
    }
  }
  long base = n * KDIM + p * 32 + fo * 2;
#pragma unroll
  for (int a = 0; a < AA; ++a) {
    __hip_bfloat16 hx = __float2bfloat16(sx_acc[a]);
    __hip_bfloat16 hy = __float2bfloat16(sy_acc[a]);
    unsigned u = (unsigned)*(unsigned short*)&hx | ((unsigned)*(unsigned short*)&hy << 16);
    __builtin_nontemporal_store(u, (unsigned*)(Sout + base + a * FF));
  }
}

// ---------- GEMM (radix-2, occupancy-2): block = 128 rows x (128E + 128O cols), K=512.
// 256 thr = 4 waves (2M x 2N); per wave 64 rows x (64E + 64O). 2 LDS buffers (64KB) +
// 80KB conflict-reduced epilogue region -> 2 blocks/CU. [375.6us-run config — frozen]
// grid (8, 392): cb = by&7 (col-block = 16 o-values), mt = (by>>3)*8 + bx (XCD A-share)
__global__ __launch_bounds__(256, 2) void gemm_kernel(
    const __hip_bfloat16* __restrict__ Sh,
    const __hip_bfloat16* __restrict__ Bh,
    const float* __restrict__ bias,
    float* __restrict__ out) {
  int bx = blockIdx.x;
  int by = blockIdx.y;
  int cb = by & 7;
  int mt = ((by >> 3) << 3) + bx;
  if (mt >= 391) return;
  int row0 = mt * 128;
  int cE0 = cb * 128;

  int tid = threadIdx.x;
  int lane = tid & 63;
  int wid = tid >> 6;
  int wave_m = wid >> 1;   // 0..1
  int wave_n = wid & 1;    // 0..1

  // [0,32K) buf0, [32K,64K) buf1; each buf: Sp 8K | Sm 8K | BE 8K | BO 8K.
  // After K-loop: epilogue lout = 128 nodes x 156 floats (79872 B total).
  __shared__ __align__(16) char lds[79872];

  long srcSp[2], srcB[2];
  int dstA[2], dstBd[2];
#pragma unroll
  for (int i = 0; i < 2; ++i) {
    int li = i * 256 + tid;
    int r = li >> 2, sp = li & 3;
    int sl = sp ^ ((r >> 1) & 3);
    int rowA = row0 + r;
    if (rowA >= NN) rowA = NN - 1;
    srcSp[i] = (long)rowA * KDIM + sl * 8;
    dstA[i] = li * 16;
    srcB[i] = (long)(cE0 + r) * KB + sl * 8;
    dstBd[i] = 16384 + li * 16;
  }
  int offA[4], offB[4];
#pragma unroll
  for (int m = 0; m < 4; ++m) {
    int r = wave_m * 64 + m * 16 + (lane & 15);
    int phys = (lane >> 4) ^ ((r >> 1) & 3);
    offA[m] = r * 64 + phys * 16;
  }
#pragma unroll
  for (int n = 0; n < 4; ++n) {
    int c = wave_n * 64 + n * 16 + (lane & 15);
    int phys = (lane >> 4) ^ ((c >> 1) & 3);
    offB[n] = 16384 + c * 64 + phys * 16;
  }

  f32x4 acc[4][8];
#pragma unroll
  for (int m = 0; m < 4; ++m)
#pragma unroll
    for (int q = 0; q < 8; ++q) acc[m][q] = (f32x4){0.f, 0.f, 0.f, 0.f};

  // stage step T into buffer T&1: Sp, Sm, BE, BO (8 loads/thread)
#define STAGE(T)                                                              \
  {                                                                           \
    char* base_ = lds + ((T) & 1) * 32768;                                    \
    long k0_ = (long)(T) * 32;                                                \
    _Pragma("unroll") for (int i_ = 0; i_ < 2; ++i_)                          \
        gload_lds16(Sh + srcSp[i_] + k0_, base_ + dstA[i_]);                  \
    _Pragma("unroll") for (int i_ = 0; i_ < 2; ++i_)                          \
        gload_lds16(Sh + srcSp[i_] + 512 + k0_, base_ + 8192 + dstA[i_]);     \
    _Pragma("unroll") for (int i_ = 0; i_ < 2; ++i_)                          \
        gload_lds16(Bh + srcB[i_] + k0_, base_ + dstBd[i_]);                  \
    _Pragma("unroll") for (int i_ = 0; i_ < 2; ++i_)                          \
        gload_lds16(Bh + srcB[i_] + (long)1024 * KB + k0_,                    \
                    base_ + 8192 + dstBd[i_]);                                \
  }

#define GSTEP(STP, DOSTAGE)                                                   \
  {                                                                           \
    const char* cbuf = lds + ((STP) & 1) * 32768;                             \
    asm volatile("s_waitcnt vmcnt(0)" ::: "memory");                          \
    __builtin_amdgcn_sched_barrier(0);                                        \
    __builtin_amdgcn_s_barrier();                                             \
    __builtin_amdgcn_sched_barrier(0);                                        \
    if (DOSTAGE) STAGE((STP) + 1)                                             \
    __builtin_amdgcn_sched_barrier(0);                                        \
    short8 aE[4], aO[4], bE[4], bO[4];                                        \
    _Pragma("unroll") for (int m_ = 0; m_ < 4; ++m_) {                        \
      aE[m_] = *(const short8*)(cbuf + offA[m_]);                             \
      aO[m_] = *(const short8*)(cbuf + offA[m_] + 8192);                      \
    }                                                                         \
    _Pragma("unroll") for (int n_ = 0; n_ < 4; ++n_) {                        \
      bE[n_] = *(const short8*)(cbuf + offB[n_]);                             \
      bO[n_] = *(const short8*)(cbuf + offB[n_] + 8192);                      \
    }                                                                         \
    __builtin_amdgcn_s_setprio(1);                                            \
    _Pragma("unroll") for (int m_ = 0; m_ < 4; ++m_)                          \
        _Pragma("unroll") for (int n_ = 0; n_ < 4; ++n_) {                    \
      acc[m_][n_] = __builtin_amdgcn_mfma_f32_16x16x32_bf16(                  \
          aE[m_], bE[n_], acc[m_][n_], 0, 0, 0);                              \
      acc[m_][n_ + 4] = __builtin_amdgcn_mfma_f32_16x16x32_bf16(              \
          aO[m_], bO[n_], acc[m_][n_ + 4], 0, 0, 0);                          \
    }                                                                         \
    __builtin_amdgcn_s_setprio(0);                                            \
    __builtin_amdgcn_sched_barrier(0);                                        \
  }

  STAGE(0)
  GSTEP(0, 1)  GSTEP(1, 1)  GSTEP(2, 1)  GSTEP(3, 1)
  GSTEP(4, 1)  GSTEP(5, 1)  GSTEP(6, 1)  GSTEP(7, 1)
  GSTEP(8, 1)  GSTEP(9, 1)  GSTEP(10, 1) GSTEP(11, 1)
  GSTEP(12, 1) GSTEP(13, 1) GSTEP(14, 1) GSTEP(15, 0)

  // ---- epilogue phase 1: z = E +- O, +40*bias, relu, t-sum via shfl_xor(4),
  //      stage to lout[node*156 + kr*20 + o_l] (conflict-reduced layout) ----
  __syncthreads();
  float* lout = (float*)lds;
  int c = lane & 15;
  int t = (c >> 2) & 1;
  int j = c & 3;
  int hi = lane >> 4;
  float bq[4];
#pragma unroll
  for (int n = 0; n < 4; ++n) {
    int o_l = wave_n * 8 + n * 2 + (c >> 3);
    bq[n] = 40.f * bias[t * OO + cb * 16 + o_l];
  }
#pragma unroll
  for (int m = 0; m < 4; ++m) {
#pragma unroll
    for (int n = 0; n < 4; ++n) {
      int o_l = wave_n * 8 + n * 2 + (c >> 3);
#pragma unroll
      for (int i = 0; i < 4; ++i) {
        float zE = acc[m][n][i];
        float zO = acc[m][n + 4][i];
        float rlo = fmaxf(zE + zO + bq[n], 0.f);
        float rhi = fmaxf(zE - zO + bq[n], 0.f);
        rlo += __shfl_xor(rlo, 4);
        rhi += __shfl_xor(rhi, 4);
        if (!(lane & 4)) {
          int node = wave_m * 64 + m * 16 + hi * 4 + i;
          lout[node * 156 + j * 20 + o_l] = rlo;
          lout[node * 156 + (j + 4) * 20 + o_l] = rhi;
        }
      }
    }
  }
  __syncthreads();

  // ---- epilogue phase 2: coalesced float4 stores (64B per (node,kr)) ----
#pragma unroll
  for (int it = 0; it < 16; ++it) {
    int gi = it * 256 + tid;
    int node = gi >> 5;
    int rem = gi & 31;
    int kr = rem >> 2, o4 = rem & 3;
    int grow = row0 + node;
    if (grow < NN) {
      f32x4 v = *(const f32x4*)(lout + node * 156 + kr * 20 + o4 * 4);
      long gaddr = (long)grow * 1024 + kr * 128 + cb * 16 + o4 * 4;
      __builtin_nontemporal_store(v, (f32x4*)(out + gaddr));
    }
  }
}

extern "C" void kernel_launch(void* const* d_in, const int* in_sizes, int n_in,
                              void* d_out, int out_size, void* d_ws, size_t ws_size,
                              hipStream_t stream) {
  const float* mesh   = (const float*)d_in[0];
  const float* bary_w = (const float*)d_in[1];
  const float* W      = (const float*)d_in[2];
  const float* bias   = (const float*)d_in[3];
  const float* coeffs = (const float*)d_in[4];
  const int* bidx     = (const int*)d_in[5];
  float* out = (float*)d_out;
  char* ws = (char*)d_ws;

  __hip_bfloat16* meshq = (__hip_bfloat16*)ws;                    // 12,800,000 B
  float* G              = (float*)(ws + 12800000);                // 1,280 B
  __hip_bfloat16* Bh    = (__hip_bfloat16*)(ws + 12801280);       // 2,097,152 B (slot 4MB)
  __hip_bfloat16* Smat  = (__hip_bfloat16*)(ws + 16995584);       // 102,400,000 B
  unsigned* packb       = (unsigned*)(ws + 119395584);            // 24,000,000 B

  int do_pack = (ws_size >= 143395584UL) ? 1 : 0;

  prep_kernel<<<dim3(2048), dim3(256), 0, stream>>>(mesh, coeffs, W, bary_w, bidx,
                                                    meshq, G, Bh, packb, do_pack);
  if (do_pack) {
    for (int p = 0; p < 4; ++p)
      s_pass_packed<<<dim3(1563), dim3(256), 0, stream>>>(meshq, packb, G, Smat, p);
  } else {
    for (int p = 0; p < 4; ++p)
      s_pass_kernel<<<dim3(3125), dim3(256), 0, stream>>>(meshq, bary_w, bidx, G, Smat, p);
  }
  gemm_kernel<<<dim3(8, 392), dim3(256), 0, stream>>>(Smat, Bh, bias, out);
}

// Round 16
// 381.656 us; speedup vs baseline: 3.6796x; 1.0369x over previous
//
#include <hip/hip_runtime.h>
#include <hip/hip_bf16.h>
#include <stdint.h>

#define NN 50000
#define RR 5
#define AA 8
#define FF 128
#define TT 2
#define OO 128
#define KDIM 1024   // 8 planes * F
#define KB 512      // K per half (E or O)
#define RA 40       // R*A

typedef __attribute__((ext_vector_type(8))) short short8;
typedef __attribute__((ext_vector_type(4))) float f32x4;
typedef __attribute__((ext_vector_type(2))) float f32x2;
typedef __attribute__((ext_vector_type(4))) int i32x4;
typedef __attribute__((ext_vector_type(2))) unsigned u32x2;

#if __has_builtin(__builtin_elementwise_fma)
__device__ inline f32x2 pk_fma(f32x2 a, f32x2 b, f32x2 c) {
  return __builtin_elementwise_fma(a, b, c);
}
#else
__device__ inline f32x2 pk_fma(f32x2 a, f32x2 b, f32x2 c) {
  f32x2 d;
  asm("v_pk_fma_f32 %0, %1, %2, %3" : "=v"(d) : "v"(a), "v"(b), "v"(c));
  return d;
}
#endif

__device__ inline void gload_lds16(const void* g, void* l) {
  __builtin_amdgcn_global_load_lds(
      (const __attribute__((address_space(1))) unsigned int*)g,
      (__attribute__((address_space(3))) unsigned int*)l, 16, 0, 0);
}

// ---------- prep: mesh->bf16 sliced, G (radix-2 mix), B2 (E/O weights in
// MFMA-fragment-major layout), packed bary ----------
// B2 element index e: sub = e&7, lane = (e>>3)&63, kt = (e>>9)&15,
// cg = (e>>13)&63, half = e>>19.  col = cg*16 + (lane&15) (within half),
// k = kt*32 + (lane>>4)*8 + sub.  A wave's fragment = 64 lanes x 16B contiguous.
__global__ void prep_kernel(const float* __restrict__ mesh,
                            const float* __restrict__ coeffs,
                            const float* __restrict__ W,
                            const float* __restrict__ bary_w,
                            const int* __restrict__ bary_idx,
                            __hip_bfloat16* __restrict__ meshq,  // [4][N][32]
                            float* __restrict__ G,               // [8][40]
                            __hip_bfloat16* __restrict__ B2,     // 2MB frag-major
                            unsigned* __restrict__ packb,
                            int do_pack) {
  int tid = blockIdx.x * blockDim.x + threadIdx.x;
  int stride = gridDim.x * blockDim.x;
  for (int i = tid; i < NN * FF; i += stride) {
    int n = i >> 7, f = i & 127;
    int p = f >> 5, fo = f & 31;
    meshq[((long)p * NN + n) * 32 + fo] = __float2bfloat16(mesh[i]);
  }
  // G[p][k]: p<4 -> C2[p]+C2[p+4];  p>=4 -> C2[p-4]-C2[p]   (C2 = sum_r coeffs)
  for (int i = tid; i < AA * RA; i += stride) {
    int p = i / RA, k = i % RA;
    int a = p & 3;
    float s1 = 0.f, s2 = 0.f;
    for (int r = 0; r < RR; ++r) {
      s1 += coeffs[(r * AA + a) * RA + k];
      s2 += coeffs[(r * AA + a + 4) * RA + k];
    }
    G[i] = (p < 4) ? (s1 + s2) : (s1 - s2);
  }
  // B2: col c = o*8 + t*4 + j; E: 0.5*(W[m]+W[m+4]); O: s*0.5*(W[m]-W[m+4]),
  // m=(a4+j)&3, s=-1 iff a4+j>=4
  for (int e = tid; e < 2048 * KB; e += stride) {
    int sub = e & 7;
    int lane = (e >> 3) & 63;
    int kt = (e >> 9) & 15;
    int cg = (e >> 13) & 63;
    int half = e >> 19;
    int c = cg * 16 + (lane & 15);
    int k = kt * 32 + (lane >> 4) * 8 + sub;
    int o = c >> 3, t = (c >> 2) & 1, j = c & 3;
    int a4 = k >> 7, f = k & 127;
    int m = (a4 + j) & 3;
    float w0 = W[((m * TT + t) * OO + o) * FF + f];
    float w4 = W[(((m + 4) * TT + t) * OO + o) * FF + f];
    float v;
    if (half == 0) v = 0.5f * (w0 + w4);
    else {
      v = 0.5f * (w0 - w4);
      if (a4 + j >= 4) v = -v;
    }
    B2[e] = __float2bfloat16(v);
  }
  if (do_pack) {
    for (int i = tid; i < NN * 120; i += stride) {
      __hip_bfloat16 h = __float2bfloat16(bary_w[i]);
      unsigned wb = *(unsigned short*)&h;
      packb[i] = ((unsigned)bary_idx[i] << 16) | wb;
    }
  }
}

// ---------- S pass (packed, per-slice, 4 features/lane, pk-f32 math) ----------
// [375.6us-run config — frozen; batch-prefetch variant regressed (R15)]
__global__ __launch_bounds__(256) void s_pass_packed(
    const __hip_bfloat16* __restrict__ meshq,
    const unsigned* __restrict__ packb,
    const float* __restrict__ G,
    __hip_bfloat16* __restrict__ Sout,
    int p) {
  __shared__ unsigned pk_s[32 * 120];
  __shared__ float g_s[AA * RA];
  int tid = threadIdx.x;
  long n0 = (long)blockIdx.x * 32;
  int nnode = (NN - n0 < 32) ? (int)(NN - n0) : 32;
  int nvec = nnode * 30;
  const i32x4* psrc = (const i32x4*)(packb + n0 * 120);
  for (int i = tid; i < nvec; i += 256) {
    i32x4 v = __builtin_nontemporal_load(psrc + i);
    ((i32x4*)pk_s)[i] = v;
  }
  for (int i = tid; i < AA * RA; i += 256) g_s[i] = G[i];
  __syncthreads();

  int g = tid >> 3;
  int fo = tid & 7;
  long n = n0 + g;
  if (n >= NN) return;
  const unsigned* pg = pk_s + g * 120;
  const char* mbase = (const char*)meshq + (long)p * NN * 64 + fo * 8;

  f32x2 accA[AA], accB[AA];
#pragma unroll
  for (int a = 0; a < AA; ++a) {
    accA[a] = (f32x2){0.f, 0.f};
    accB[a] = (f32x2){0.f, 0.f};
  }

#pragma unroll 2
  for (int k = 0; k < RA; ++k) {
    f32x2 sA = (f32x2){0.f, 0.f}, sB = (f32x2){0.f, 0.f};
#pragma unroll
    for (int j = 0; j < 3; ++j) {
      unsigned v = pg[k * 3 + j];
      long row = v >> 16;
      float w = __uint_as_float(v << 16);
      f32x2 wv = (f32x2){w, w};
      u32x2 u = *(const u32x2*)(mbase + row * 64);
      f32x2 lo = (f32x2){__uint_as_float(u[0] << 16),
                         __uint_as_float(u[0] & 0xffff0000u)};
      f32x2 hi = (f32x2){__uint_as_float(u[1] << 16),
                         __uint_as_float(u[1] & 0xffff0000u)};
      sA = pk_fma(wv, lo, sA);
      sB = pk_fma(wv, hi, sB);
    }
#pragma unroll
    for (int a = 0; a < AA; ++a) {
      float cc = g_s[a * RA + k];
      f32x2 cv = (f32x2){cc, cc};
      accA[a] = pk_fma(cv, sA, accA[a]);
      accB[a] = pk_fma(cv, sB, accB[a]);
    }
  }

  long base = n * KDIM + p * 32 + fo * 4;
#pragma unroll
  for (int a = 0; a < AA; ++a) {
    __hip_bfloat16 h0 = __float2bfloat16(accA[a][0]);
    __hip_bfloat16 h1 = __float2bfloat16(accA[a][1]);
    __hip_bfloat16 h2 = __float2bfloat16(accB[a][0]);
    __hip_bfloat16 h3 = __float2bfloat16(accB[a][1]);
    unsigned w0 = (unsigned)*(unsigned short*)&h0 |
                  ((unsigned)*(unsigned short*)&h1 << 16);
    unsigned w1 = (unsigned)*(unsigned short*)&h2 |
                  ((unsigned)*(unsigned short*)&h3 << 16);
    u32x2 st = (u32x2){w0, w1};
    __builtin_nontemporal_store(st, (u32x2*)(Sout + base + a * FF));
  }
}

// ---------- S pass (legacy fallback, per-slice; B2-independent) ----------
__global__ __launch_bounds__(256) void s_pass_kernel(
    const __hip_bfloat16* __restrict__ meshq,
    const float* __restrict__ bary_w,
    const int* __restrict__ bary_idx,
    const float* __restrict__ G,
    __hip_bfloat16* __restrict__ Sout,
    int p) {
  __shared__ float w_s[16 * 120];
  __shared__ int i_s[16 * 120];
  __shared__ float g_s[AA * RA];
  int tid = threadIdx.x;
  long n0 = (long)blockIdx.x * 16;
  const f32x4* wsrc = (const f32x4*)(bary_w + n0 * 120);
  const i32x4* isrc = (const i32x4*)(bary_idx + n0 * 120);
  for (int i = tid; i < 480; i += 256) {
    f32x4 wv = __builtin_nontemporal_load(wsrc + i);
    ((f32x4*)w_s)[i] = wv;
    i32x4 iv = __builtin_nontemporal_load(isrc + i);
    ((i32x4*)i_s)[i] = iv;
  }
  for (int i = tid; i < AA * RA; i += 256) g_s[i] = G[i];
  __syncthreads();
  int g = tid >> 4;
  int fo = tid & 15;
  long n = n0 + g;
  const float* wg = w_s + g * 120;
  const int* ig = i_s + g * 120;
  const char* mbase = (const char*)meshq + (long)p * NN * 64 + fo * 4;
  float sx_acc[AA], sy_acc[AA];
#pragma unroll
  for (int a = 0; a < AA; ++a) { sx_acc[a] = 0.f; sy_acc[a] = 0.f; }
#pragma unroll 2
  for (int k = 0; k < RA; ++k) {
    float sx = 0.f, sy = 0.f;
#pragma unroll
    for (int j = 0; j < 3; ++j) {
      int row = ig[k * 3 + j];
      unsigned u = *(const unsigned*)(mbase + (long)row * 64);
      float w = wg[k * 3 + j];
      sx += w * __uint_as_float(u << 16);
      sy += w * __uint_as_float(u & 0xffff0000u);
    }
#pragma unroll
    for (int a = 0; a < AA; ++a) {
      float c = g_s[a * RA + k];
      sx_acc[a] += c * sx;
      sy_acc[a] += c * sy;
    }
  }
  long base = n * KDIM + p * 32 + fo * 2;
#pragma unroll
  for (int a = 0; a < AA; ++a) {
    __hip_bfloat16 hx = __float2bfloat16(sx_acc[a]);
    __hip_bfloat16 hy = __float2bfloat16(sy_acc[a]);
    unsigned u = (unsigned)*(unsigned short*)&hx | ((unsigned)*(unsigned short*)&hy << 16);
    __builtin_nontemporal_store(u, (unsigned*)(Sout + base + a * FF));
  }
}

// ---------- GEMM (radix-2, occupancy-2, B-from-L2): block = 128 rows x
// (128E + 128O cols), K=512. 256 thr = 4 waves (2M x 2N).
// B2 (2MB, L2-resident) is read per-fragment directly into registers (1KB
// coalesced per wave-read) — NO LDS staging for B. A-only staging halves LDS
// traffic (the measured bottleneck: MfmaUtil 21% with 96KB LDS reads/step/CU).
// b-loads issued BEFORE staging each step so consuming b waits vmcnt(4), not 0.
// grid (8, 392): cb = by&7, mt = (by>>3)*8 + bx (XCD A-share)
__global__ __launch_bounds__(256, 2) void gemm_kernel(
    const __hip_bfloat16* __restrict__ Sh,
    const __hip_bfloat16* __restrict__ B2,
    const float* __restrict__ bias,
    float* __restrict__ out) {
  int bx = blockIdx.x;
  int by = blockIdx.y;
  int cb = by & 7;
  int mt = ((by >> 3) << 3) + bx;
  if (mt >= 391) return;
  int row0 = mt * 128;

  int tid = threadIdx.x;
  int lane = tid & 63;
  int wid = tid >> 6;
  int wave_m = wid >> 1;   // 0..1
  int wave_n = wid & 1;    // 0..1

  // [0,16K) buf0, [16K,32K) buf1; each buf: Sp 8K | Sm 8K.
  // After K-loop: epilogue lout = 128 nodes x 156 floats (79872 B).
  __shared__ __align__(16) char lds[79872];

  long srcSp[2];
  int dstA[2];
#pragma unroll
  for (int i = 0; i < 2; ++i) {
    int li = i * 256 + tid;
    int r = li >> 2, sp = li & 3;
    int sl = sp ^ ((r >> 1) & 3);
    int rowA = row0 + r;
    if (rowA >= NN) rowA = NN - 1;
    srcSp[i] = (long)rowA * KDIM + sl * 8;
    dstA[i] = li * 16;
  }
  int offA[4];
#pragma unroll
  for (int m = 0; m < 4; ++m) {
    int r = wave_m * 64 + m * 16 + (lane & 15);
    int phys = (lane >> 4) ^ ((r >> 1) & 3);
    offA[m] = r * 64 + phys * 16;
  }
  // B2 fragment byte offsets: ((half*64 + cg)*16 + kt)*1024 + lane*16
  const char* b2c = (const char*)B2;
  long bOffE[4], bOffO[4];
#pragma unroll
  for (int n = 0; n < 4; ++n) {
    int cg = cb * 8 + wave_n * 4 + n;
    bOffE[n] = ((long)cg * 16) * 1024 + lane * 16;
    bOffO[n] = bOffE[n] + (long)64 * 16 * 1024;
  }

  f32x4 acc[4][8];
#pragma unroll
  for (int m = 0; m < 4; ++m)
#pragma unroll
    for (int q = 0; q < 8; ++q) acc[m][q] = (f32x4){0.f, 0.f, 0.f, 0.f};

  // stage step T into buffer T&1: Sp, Sm (4 loads/thread)
#define STAGE(T)                                                              \
  {                                                                           \
    char* base_ = lds + ((T) & 1) * 16384;                                    \
    long k0_ = (long)(T) * 32;                                                \
    _Pragma("unroll") for (int i_ = 0; i_ < 2; ++i_)                          \
        gload_lds16(Sh + srcSp[i_] + k0_, base_ + dstA[i_]);                  \
    _Pragma("unroll") for (int i_ = 0; i_ < 2; ++i_)                          \
        gload_lds16(Sh + srcSp[i_] + 512 + k0_, base_ + 8192 + dstA[i_]);     \
  }

#define GSTEP(STP, DOSTAGE)                                                   \
  {                                                                           \
    const char* cbuf = lds + ((STP) & 1) * 16384;                             \
    asm volatile("s_waitcnt vmcnt(0)" ::: "memory");                          \
    __builtin_amdgcn_sched_barrier(0);                                        \
    __builtin_amdgcn_s_barrier();                                             \
    __builtin_amdgcn_sched_barrier(0);                                        \
    short8 bE[4], bO[4];                                                      \
    _Pragma("unroll") for (int n_ = 0; n_ < 4; ++n_) {                        \
      bE[n_] = *(const short8*)(b2c + bOffE[n_] + (long)(STP) * 1024);        \
      bO[n_] = *(const short8*)(b2c + bOffO[n_] + (long)(STP) * 1024);        \
    }                                                                         \
    if (DOSTAGE) STAGE((STP) + 1)                                             \
    __builtin_amdgcn_sched_barrier(0);                                        \
    short8 aE[4], aO[4];                                                      \
    _Pragma("unroll") for (int m_ = 0; m_ < 4; ++m_) {                        \
      aE[m_] = *(const short8*)(cbuf + offA[m_]);                             \
      aO[m_] = *(const short8*)(cbuf + offA[m_] + 8192);                      \
    }                                                                         \
    __builtin_amdgcn_s_setprio(1);                                            \
    _Pragma("unroll") for (int m_ = 0; m_ < 4; ++m_)                          \
        _Pragma("unroll") for (int n_ = 0; n_ < 4; ++n_) {                    \
      acc[m_][n_] = __builtin_amdgcn_mfma_f32_16x16x32_bf16(                  \
          aE[m_], bE[n_], acc[m_][n_], 0, 0, 0);                              \
      acc[m_][n_ + 4] = __builtin_amdgcn_mfma_f32_16x16x32_bf16(              \
          aO[m_], bO[n_], acc[m_][n_ + 4], 0, 0, 0);                          \
    }                                                                         \
    __builtin_amdgcn_s_setprio(0);                                            \
    __builtin_amdgcn_sched_barrier(0);                                        \
  }

  STAGE(0)
  GSTEP(0, 1)  GSTEP(1, 1)  GSTEP(2, 1)  GSTEP(3, 1)
  GSTEP(4, 1)  GSTEP(5, 1)  GSTEP(6, 1)  GSTEP(7, 1)
  GSTEP(8, 1)  GSTEP(9, 1)  GSTEP(10, 1) GSTEP(11, 1)
  GSTEP(12, 1) GSTEP(13, 1) GSTEP(14, 1) GSTEP(15, 0)

  // ---- epilogue phase 1: z = E +- O, +40*bias, relu, t-sum via shfl_xor(4),
  //      stage to lout[node*156 + kr*20 + o_l] (conflict-reduced layout) ----
  __syncthreads();
  float* lout = (float*)lds;
  int c = lane & 15;
  int t = (c >> 2) & 1;
  int j = c & 3;
  int hi = lane >> 4;
  float bq[4];
#pragma unroll
  for (int n = 0; n < 4; ++n) {
    int o_l = wave_n * 8 + n * 2 + (c >> 3);
    bq[n] = 40.f * bias[t * OO + cb * 16 + o_l];
  }
#pragma unroll
  for (int m = 0; m < 4; ++m) {
#pragma unroll
    for (int n = 0; n < 4; ++n) {
      int o_l = wave_n * 8 + n * 2 + (c >> 3);
#pragma unroll
      for (int i = 0; i < 4; ++i) {
        float zE = acc[m][n][i];
        float zO = acc[m][n + 4][i];
        float rlo = fmaxf(zE + zO + bq[n], 0.f);
        float rhi = fmaxf(zE - zO + bq[n], 0.f);
        rlo += __shfl_xor(rlo, 4);
        rhi += __shfl_xor(rhi, 4);
        if (!(lane & 4)) {
          int node = wave_m * 64 + m * 16 + hi * 4 + i;
          lout[node * 156 + j * 20 + o_l] = rlo;
          lout[node * 156 + (j + 4) * 20 + o_l] = rhi;
        }
      }
    }
  }
  __syncthreads();

  // ---- epilogue phase 2: coalesced float4 stores (64B per (node,kr)) ----
#pragma unroll
  for (int it = 0; it < 16; ++it) {
    int gi = it * 256 + tid;
    int node = gi >> 5;
    int rem = gi & 31;
    int kr = rem >> 2, o4 = rem & 3;
    int grow = row0 + node;
    if (grow < NN) {
      f32x4 v = *(const f32x4*)(lout + node * 156 + kr * 20 + o4 * 4);
      long gaddr = (long)grow * 1024 + kr * 128 + cb * 16 + o4 * 4;
      __builtin_nontemporal_store(v, (f32x4*)(out + gaddr));
    }
  }
}

extern "C" void kernel_launch(void* const* d_in, const int* in_sizes, int n_in,
                              void* d_out, int out_size, void* d_ws, size_t ws_size,
                              hipStream_t stream) {
  const float* mesh   = (const float*)d_in[0];
  const float* bary_w = (const float*)d_in[1];
  const float* W      = (const float*)d_in[2];
  const float* bias   = (const float*)d_in[3];
  const float* coeffs = (const float*)d_in[4];
  const int* bidx     = (const int*)d_in[5];
  float* out = (float*)d_out;
  char* ws = (char*)d_ws;

  __hip_bfloat16* meshq = (__hip_bfloat16*)ws;                    // 12,800,000 B
  float* G              = (float*)(ws + 12800000);                // 1,280 B
  __hip_bfloat16* B2    = (__hip_bfloat16*)(ws + 12801280);       // 2,097,152 B (slot 4MB)
  __hip_bfloat16* Smat  = (__hip_bfloat16*)(ws + 16995584);       // 102,400,000 B
  unsigned* packb       = (unsigned*)(ws + 119395584);            // 24,000,000 B

  int do_pack = (ws_size >= 143395584UL) ? 1 : 0;

  prep_kernel<<<dim3(2048), dim3(256), 0, stream>>>(mesh, coeffs, W, bary_w, bidx,
                                                    meshq, G, B2, packb, do_pack);
  if (do_pack) {
    for (int p = 0; p < 4; ++p)
      s_pass_packed<<<dim3(1563), dim3(256), 0, stream>>>(meshq, packb, G, Smat, p);
  } else {
    // NOTE: legacy fallback pairs with the OLD row-major Bh layout; B2 here is
    // frag-major, so the fallback path cannot be used with this gemm. The
    // harness workspace is large enough in practice (do_pack==1); guard anyway.
    for (int p = 0; p < 4; ++p)
      s_pass_kernel<<<dim3(3125), dim3(256), 0, stream>>>(meshq, bary_w, bidx, G, Smat, p);
  }
  gemm_kernel<<<dim3(8, 392), dim3(256), 0, stream>>>(Smat, B2, bias, out);
}

// Round 17
// 372.886 us; speedup vs baseline: 3.7661x; 1.0235x over previous
//
#include <hip/hip_runtime.h>
#include <hip/hip_bf16.h>
#include <stdint.h>

#define NN 50000
#define RR 5
#define AA 8
#define FF 128
#define TT 2
#define OO 128
#define KDIM 1024   // 8 planes * F
#define KB 512      // K per half (E or O)
#define RA 40       // R*A

typedef __attribute__((ext_vector_type(8))) short short8;
typedef __attribute__((ext_vector_type(4))) float f32x4;
typedef __attribute__((ext_vector_type(2))) float f32x2;
typedef __attribute__((ext_vector_type(4))) int i32x4;
typedef __attribute__((ext_vector_type(2))) unsigned u32x2;

#if __has_builtin(__builtin_elementwise_fma)
__device__ inline f32x2 pk_fma(f32x2 a, f32x2 b, f32x2 c) {
  return __builtin_elementwise_fma(a, b, c);
}
#else
__device__ inline f32x2 pk_fma(f32x2 a, f32x2 b, f32x2 c) {
  f32x2 d;
  asm("v_pk_fma_f32 %0, %1, %2, %3" : "=v"(d) : "v"(a), "v"(b), "v"(c));
  return d;
}
#endif

__device__ inline void gload_lds16(const void* g, void* l) {
  __builtin_amdgcn_global_load_lds(
      (const __attribute__((address_space(1))) unsigned int*)g,
      (__attribute__((address_space(3))) unsigned int*)l, 16, 0, 0);
}

// ---------- prep: mesh->bf16 sliced, G (radix-2 mix), B2 (E/O weights in
// MFMA-fragment-major layout), packed bary ----------
__global__ void prep_kernel(const float* __restrict__ mesh,
                            const float* __restrict__ coeffs,
                            const float* __restrict__ W,
                            const float* __restrict__ bary_w,
                            const int* __restrict__ bary_idx,
                            __hip_bfloat16* __restrict__ meshq,  // [4][N][32]
                            float* __restrict__ G,               // [8][40]
                            __hip_bfloat16* __restrict__ B2,     // 2MB frag-major
                            unsigned* __restrict__ packb,
                            int do_pack) {
  int tid = blockIdx.x * blockDim.x + threadIdx.x;
  int stride = gridDim.x * blockDim.x;
  for (int i = tid; i < NN * FF; i += stride) {
    int n = i >> 7, f = i & 127;
    int p = f >> 5, fo = f & 31;
    meshq[((long)p * NN + n) * 32 + fo] = __float2bfloat16(mesh[i]);
  }
  // G[p][k]: p<4 -> C2[p]+C2[p+4];  p>=4 -> C2[p-4]-C2[p]   (C2 = sum_r coeffs)
  for (int i = tid; i < AA * RA; i += stride) {
    int p = i / RA, k = i % RA;
    int a = p & 3;
    float s1 = 0.f, s2 = 0.f;
    for (int r = 0; r < RR; ++r) {
      s1 += coeffs[(r * AA + a) * RA + k];
      s2 += coeffs[(r * AA + a + 4) * RA + k];
    }
    G[i] = (p < 4) ? (s1 + s2) : (s1 - s2);
  }
  // B2: e -> sub=e&7, lane=(e>>3)&63, kt=(e>>9)&15, cg=(e>>13)&63, half=e>>19.
  // col c = cg*16+(lane&15), k = kt*32+(lane>>4)*8+sub; c = o*8+t*4+j.
  for (int e = tid; e < 2048 * KB; e += stride) {
    int sub = e & 7;
    int lane = (e >> 3) & 63;
    int kt = (e >> 9) & 15;
    int cg = (e >> 13) & 63;
    int half = e >> 19;
    int c = cg * 16 + (lane & 15);
    int k = kt * 32 + (lane >> 4) * 8 + sub;
    int o = c >> 3, t = (c >> 2) & 1, j = c & 3;
    int a4 = k >> 7, f = k & 127;
    int m = (a4 + j) & 3;
    float w0 = W[((m * TT + t) * OO + o) * FF + f];
    float w4 = W[(((m + 4) * TT + t) * OO + o) * FF + f];
    float v;
    if (half == 0) v = 0.5f * (w0 + w4);
    else {
      v = 0.5f * (w0 - w4);
      if (a4 + j >= 4) v = -v;
    }
    B2[e] = __float2bfloat16(v);
  }
  if (do_pack) {
    for (int i = tid; i < NN * 120; i += stride) {
      __hip_bfloat16 h = __float2bfloat16(bary_w[i]);
      unsigned wb = *(unsigned short*)&h;
      packb[i] = ((unsigned)bary_idx[i] << 16) | wb;
    }
  }
}

// ---------- S pass (packed, per-slice, 4 features/lane, pk-f32 math) ----------
// [375.6us-run config — frozen]
__global__ __launch_bounds__(256) void s_pass_packed(
    const __hip_bfloat16* __restrict__ meshq,
    const unsigned* __restrict__ packb,
    const float* __restrict__ G,
    __hip_bfloat16* __restrict__ Sout,
    int p) {
  __shared__ unsigned pk_s[32 * 120];
  __shared__ float g_s[AA * RA];
  int tid = threadIdx.x;
  long n0 = (long)blockIdx.x * 32;
  int nnode = (NN - n0 < 32) ? (int)(NN - n0) : 32;
  int nvec = nnode * 30;
  const i32x4* psrc = (const i32x4*)(packb + n0 * 120);
  for (int i = tid; i < nvec; i += 256) {
    i32x4 v = __builtin_nontemporal_load(psrc + i);
    ((i32x4*)pk_s)[i] = v;
  }
  for (int i = tid; i < AA * RA; i += 256) g_s[i] = G[i];
  __syncthreads();

  int g = tid >> 3;
  int fo = tid & 7;
  long n = n0 + g;
  if (n >= NN) return;
  const unsigned* pg = pk_s + g * 120;
  const char* mbase = (const char*)meshq + (long)p * NN * 64 + fo * 8;

  f32x2 accA[AA], accB[AA];
#pragma unroll
  for (int a = 0; a < AA; ++a) {
    accA[a] = (f32x2){0.f, 0.f};
    accB[a] = (f32x2){0.f, 0.f};
  }

#pragma unroll 2
  for (int k = 0; k < RA; ++k) {
    f32x2 sA = (f32x2){0.f, 0.f}, sB = (f32x2){0.f, 0.f};
#pragma unroll
    for (int j = 0; j < 3; ++j) {
      unsigned v = pg[k * 3 + j];
      long row = v >> 16;
      float w = __uint_as_float(v << 16);
      f32x2 wv = (f32x2){w, w};
      u32x2 u = *(const u32x2*)(mbase + row * 64);
      f32x2 lo = (f32x2){__uint_as_float(u[0] << 16),
                         __uint_as_float(u[0] & 0xffff0000u)};
      f32x2 hi = (f32x2){__uint_as_float(u[1] << 16),
                         __uint_as_float(u[1] & 0xffff0000u)};
      sA = pk_fma(wv, lo, sA);
      sB = pk_fma(wv, hi, sB);
    }
#pragma unroll
    for (int a = 0; a < AA; ++a) {
      float cc = g_s[a * RA + k];
      f32x2 cv = (f32x2){cc, cc};
      accA[a] = pk_fma(cv, sA, accA[a]);
      accB[a] = pk_fma(cv, sB, accB[a]);
    }
  }

  long base = n * KDIM + p * 32 + fo * 4;
#pragma unroll
  for (int a = 0; a < AA; ++a) {
    __hip_bfloat16 h0 = __float2bfloat16(accA[a][0]);
    __hip_bfloat16 h1 = __float2bfloat16(accA[a][1]);
    __hip_bfloat16 h2 = __float2bfloat16(accB[a][0]);
    __hip_bfloat16 h3 = __float2bfloat16(accB[a][1]);
    unsigned w0 = (unsigned)*(unsigned short*)&h0 |
                  ((unsigned)*(unsigned short*)&h1 << 16);
    unsigned w1 = (unsigned)*(unsigned short*)&h2 |
                  ((unsigned)*(unsigned short*)&h3 << 16);
    u32x2 st = (u32x2){w0, w1};
    __builtin_nontemporal_store(st, (u32x2*)(Sout + base + a * FF));
  }
}

// ---------- S pass (legacy fallback, per-slice) ----------
__global__ __launch_bounds__(256) void s_pass_kernel(
    const __hip_bfloat16* __restrict__ meshq,
    const float* __restrict__ bary_w,
    const int* __restrict__ bary_idx,
    const float* __restrict__ G,
    __hip_bfloat16* __restrict__ Sout,
    int p) {
  __shared__ float w_s[16 * 120];
  __shared__ int i_s[16 * 120];
  __shared__ float g_s[AA * RA];
  int tid = threadIdx.x;
  long n0 = (long)blockIdx.x * 16;
  const f32x4* wsrc = (const f32x4*)(bary_w + n0 * 120);
  const i32x4* isrc = (const i32x4*)(bary_idx + n0 * 120);
  for (int i = tid; i < 480; i += 256) {
    f32x4 wv = __builtin_nontemporal_load(wsrc + i);
    ((f32x4*)w_s)[i] = wv;
    i32x4 iv = __builtin_nontemporal_load(isrc + i);
    ((i32x4*)i_s)[i] = iv;
  }
  for (int i = tid; i < AA * RA; i += 256) g_s[i] = G[i];
  __syncthreads();
  int g = tid >> 4;
  int fo = tid & 15;
  long n = n0 + g;
  const float* wg = w_s + g * 120;
  const int* ig = i_s + g * 120;
  const char* mbase = (const char*)meshq + (long)p * NN * 64 + fo * 4;
  float sx_acc[AA], sy_acc[AA];
#pragma unroll
  for (int a = 0; a < AA; ++a) { sx_acc[a] = 0.f; sy_acc[a] = 0.f; }
#pragma unroll 2
  for (int k = 0; k < RA; ++k) {
    float sx = 0.f, sy = 0.f;
#pragma unroll
    for (int j = 0; j < 3; ++j) {
      int row = ig[k * 3 + j];
      unsigned u = *(const unsigned*)(mbase + (long)row * 64);
      float w = wg[k * 3 + j];
      sx += w * __uint_as_float(u << 16);
      sy += w * __uint_as_float(u & 0xffff0000u);
    }
#pragma unroll
    for (int a = 0; a < AA; ++a) {
      float c = g_s[a * RA + k];
      sx_acc[a] += c * sx;
      sy_acc[a] += c * sy;
    }
  }
  long base = n * KDIM + p * 32 + fo * 2;
#pragma unroll
  for (int a = 0; a < AA; ++a) {
    __hip_bfloat16 hx = __float2bfloat16(sx_acc[a]);
    __hip_bfloat16 hy = __float2bfloat16(sy_acc[a]);
    unsigned u = (unsigned)*(unsigned short*)&hx | ((unsigned)*(unsigned short*)&hy << 16);
    __builtin_nontemporal_store(u, (unsigned*)(Sout + base + a * FF));
  }
}

// ---------- GEMM (radix-2, B-from-L2, SMALL-LDS high-occupancy):
// block = 128 rows x (128E + 128O cols), K=512; 256 thr = 4 waves (2M x 2N).
// LDS = 32KB ONLY (2 x 16KB A-buffers; epilogue chunks reuse them) ->
// 5 blocks/CU (was 2 at 80KB) = ~20 waves/CU. The measured limiter was
// occupancy (20%): barrier/drain latency had no other waves to hide behind.
// grid (8, 392): cb = by&7, mt = (by>>3)*8 + bx (XCD A-share)
__global__ __launch_bounds__(256, 2) void gemm_kernel(
    const __hip_bfloat16* __restrict__ Sh,
    const __hip_bfloat16* __restrict__ B2,
    const float* __restrict__ bias,
    float* __restrict__ out) {
  int bx = blockIdx.x;
  int by = blockIdx.y;
  int cb = by & 7;
  int mt = ((by >> 3) << 3) + bx;
  if (mt >= 391) return;
  int row0 = mt * 128;

  int tid = threadIdx.x;
  int lane = tid & 63;
  int wid = tid >> 6;
  int wave_m = wid >> 1;   // 0..1
  int wave_n = wid & 1;    // 0..1

  // [0,16K) buf0, [16K,32K) buf1; each buf: Sp 8K | Sm 8K.
  // Epilogue (chunked by m): lout = 32 rows x 156 floats (19968 B), reuses base.
  __shared__ __align__(16) char lds[32768];

  long srcSp[2];
  int dstA[2];
#pragma unroll
  for (int i = 0; i < 2; ++i) {
    int li = i * 256 + tid;
    int r = li >> 2, sp = li & 3;
    int sl = sp ^ ((r >> 1) & 3);
    int rowA = row0 + r;
    if (rowA >= NN) rowA = NN - 1;
    srcSp[i] = (long)rowA * KDIM + sl * 8;
    dstA[i] = li * 16;
  }
  int offA[4];
#pragma unroll
  for (int m = 0; m < 4; ++m) {
    int r = wave_m * 64 + m * 16 + (lane & 15);
    int phys = (lane >> 4) ^ ((r >> 1) & 3);
    offA[m] = r * 64 + phys * 16;
  }
  // B2 fragment byte offsets: ((half*64 + cg)*16 + kt)*1024 + lane*16
  const char* b2c = (const char*)B2;
  long bOffE[4], bOffO[4];
#pragma unroll
  for (int n = 0; n < 4; ++n) {
    int cg = cb * 8 + wave_n * 4 + n;
    bOffE[n] = ((long)cg * 16) * 1024 + lane * 16;
    bOffO[n] = bOffE[n] + (long)64 * 16 * 1024;
  }

  f32x4 acc[4][8];
#pragma unroll
  for (int m = 0; m < 4; ++m)
#pragma unroll
    for (int q = 0; q < 8; ++q) acc[m][q] = (f32x4){0.f, 0.f, 0.f, 0.f};

  // stage step T into buffer T&1: Sp, Sm (4 loads/thread)
#define STAGE(T)                                                              \
  {                                                                           \
    char* base_ = lds + ((T) & 1) * 16384;                                    \
    long k0_ = (long)(T) * 32;                                                \
    _Pragma("unroll") for (int i_ = 0; i_ < 2; ++i_)                          \
        gload_lds16(Sh + srcSp[i_] + k0_, base_ + dstA[i_]);                  \
    _Pragma("unroll") for (int i_ = 0; i_ < 2; ++i_)                          \
        gload_lds16(Sh + srcSp[i_] + 512 + k0_, base_ + 8192 + dstA[i_]);     \
  }

#define GSTEP(STP, DOSTAGE)                                                   \
  {                                                                           \
    const char* cbuf = lds + ((STP) & 1) * 16384;                             \
    asm volatile("s_waitcnt vmcnt(0)" ::: "memory");                          \
    __builtin_amdgcn_sched_barrier(0);                                        \
    __builtin_amdgcn_s_barrier();                                             \
    __builtin_amdgcn_sched_barrier(0);                                        \
    short8 bE[4], bO[4];                                                      \
    _Pragma("unroll") for (int n_ = 0; n_ < 4; ++n_) {                        \
      bE[n_] = *(const short8*)(b2c + bOffE[n_] + (long)(STP) * 1024);        \
      bO[n_] = *(const short8*)(b2c + bOffO[n_] + (long)(STP) * 1024);        \
    }                                                                         \
    if (DOSTAGE) STAGE((STP) + 1)                                             \
    __builtin_amdgcn_sched_barrier(0);                                        \
    short8 aE[4], aO[4];                                                      \
    _Pragma("unroll") for (int m_ = 0; m_ < 4; ++m_) {                        \
      aE[m_] = *(const short8*)(cbuf + offA[m_]);                             \
      aO[m_] = *(const short8*)(cbuf + offA[m_] + 8192);                      \
    }                                                                         \
    __builtin_amdgcn_s_setprio(1);                                            \
    _Pragma("unroll") for (int m_ = 0; m_ < 4; ++m_)                          \
        _Pragma("unroll") for (int n_ = 0; n_ < 4; ++n_) {                    \
      acc[m_][n_] = __builtin_amdgcn_mfma_f32_16x16x32_bf16(                  \
          aE[m_], bE[n_], acc[m_][n_], 0, 0, 0);                              \
      acc[m_][n_ + 4] = __builtin_amdgcn_mfma_f32_16x16x32_bf16(              \
          aO[m_], bO[n_], acc[m_][n_ + 4], 0, 0, 0);                          \
    }                                                                         \
    __builtin_amdgcn_s_setprio(0);                                            \
    __builtin_amdgcn_sched_barrier(0);                                        \
  }

  STAGE(0)
  GSTEP(0, 1)  GSTEP(1, 1)  GSTEP(2, 1)  GSTEP(3, 1)
  GSTEP(4, 1)  GSTEP(5, 1)  GSTEP(6, 1)  GSTEP(7, 1)
  GSTEP(8, 1)  GSTEP(9, 1)  GSTEP(10, 1) GSTEP(11, 1)
  GSTEP(12, 1) GSTEP(13, 1) GSTEP(14, 1) GSTEP(15, 0)

  // ---- epilogue, chunked by m (4 chunks x 32 rows; lout 19968B reuses LDS):
  // z = E +- O, +40*bias, relu, t-sum shfl_xor(4) -> lout -> coalesced copy ----
  float* lout = (float*)lds;
  int c = lane & 15;
  int t = (c >> 2) & 1;
  int j = c & 3;
  int hi = lane >> 4;
  float bq[4];
#pragma unroll
  for (int n = 0; n < 4; ++n) {
    int o_l = wave_n * 8 + n * 2 + (c >> 3);
    bq[n] = 40.f * bias[t * OO + cb * 16 + o_l];
  }
#pragma unroll
  for (int m = 0; m < 4; ++m) {
    __syncthreads();  // prior chunk copy done / K-loop LDS reads done
#pragma unroll
    for (int n = 0; n < 4; ++n) {
      int o_l = wave_n * 8 + n * 2 + (c >> 3);
#pragma unroll
      for (int i = 0; i < 4; ++i) {
        float zE = acc[m][n][i];
        float zO = acc[m][n + 4][i];
        float rlo = fmaxf(zE + zO + bq[n], 0.f);
        float rhi = fmaxf(zE - zO + bq[n], 0.f);
        rlo += __shfl_xor(rlo, 4);
        rhi += __shfl_xor(rhi, 4);
        if (!(lane & 4)) {
          int cl = wave_m * 16 + hi * 4 + i;
          lout[cl * 156 + j * 20 + o_l] = rlo;
          lout[cl * 156 + (j + 4) * 20 + o_l] = rhi;
        }
      }
    }
    __syncthreads();
    // copy chunk: 32 rows x 8 kr x 4 float4 = 1024 float4, 256 thr -> 4 iters
#pragma unroll
    for (int it = 0; it < 4; ++it) {
      int gi = it * 256 + tid;
      int cl = gi >> 5;
      int rem = gi & 31;
      int kr = rem >> 2, q = rem & 3;
      int grow = row0 + (cl >> 4) * 64 + m * 16 + (cl & 15);
      if (grow < NN) {
        f32x4 v = *(const f32x4*)(lout + cl * 156 + kr * 20 + q * 4);
        long gaddr = (long)grow * 1024 + kr * 128 + cb * 16 + q * 4;
        __builtin_nontemporal_store(v, (f32x4*)(out + gaddr));
      }
    }
  }
}

extern "C" void kernel_launch(void* const* d_in, const int* in_sizes, int n_in,
                              void* d_out, int out_size, void* d_ws, size_t ws_size,
                              hipStream_t stream) {
  const float* mesh   = (const float*)d_in[0];
  const float* bary_w = (const float*)d_in[1];
  const float* W      = (const float*)d_in[2];
  const float* bias   = (const float*)d_in[3];
  const float* coeffs = (const float*)d_in[4];
  const int* bidx     = (const int*)d_in[5];
  float* out = (float*)d_out;
  char* ws = (char*)d_ws;

  __hip_bfloat16* meshq = (__hip_bfloat16*)ws;                    // 12,800,000 B
  float* G              = (float*)(ws + 12800000);                // 1,280 B
  __hip_bfloat16* B2    = (__hip_bfloat16*)(ws + 12801280);       // 2,097,152 B (slot 4MB)
  __hip_bfloat16* Smat  = (__hip_bfloat16*)(ws + 16995584);       // 102,400,000 B
  unsigned* packb       = (unsigned*)(ws + 119395584);            // 24,000,000 B

  int do_pack = (ws_size >= 143395584UL) ? 1 : 0;

  prep_kernel<<<dim3(2048), dim3(256), 0, stream>>>(mesh, coeffs, W, bary_w, bidx,
                                                    meshq, G, B2, packb, do_pack);
  if (do_pack) {
    for (int p = 0; p < 4; ++p)
      s_pass_packed<<<dim3(1563), dim3(256), 0, stream>>>(meshq, packb, G, Smat, p);
  } else {
    for (int p = 0; p < 4; ++p)
      s_pass_kernel<<<dim3(3125), dim3(256), 0, stream>>>(meshq, bary_w, bidx, G, Smat, p);
  }
  gemm_kernel<<<dim3(8, 392), dim3(256), 0, stream>>>(Smat, B2, bias, out);
}